// Round 2
// baseline (799.874 us; speedup 1.0000x reference)
//
#include <hip/hip_runtime.h>
#include <hip/hip_bf16.h>

using bf16 = __hip_bfloat16;
typedef __attribute__((ext_vector_type(4))) unsigned short ushort4v;

#define N_  2
#define C_  512
#define T_  96
#define H_  14
#define W_  14
#define HW_ 196
#define RC_ 32
#define B_  (N_*T_)    // 192
#define SC_ (T_*HW_)   // 18816 elems per channel
#define SN_ (C_*SC_)   // elems per batch
#define XTOT (N_*C_*T_*HW_)  // 19267584

// fp32 vec arena offsets
#define VQB   0
#define VKB   512
#define VVB   1024
#define VCB   1536
#define VQRY  2048
#define VSAB  2560   // 96 (3x32)
#define VW2   2688   // 6
#define VW4   2696   // 3
#define VWTS  2700   // 3
#define VECS_TOTAL 2720

__device__ __forceinline__ float b2f(bf16 v){ return __bfloat162float(v); }
__device__ __forceinline__ float u2f(unsigned short u){ return __uint_as_float(((unsigned)u)<<16); }
__device__ __forceinline__ float sigm(float x){ return 1.f/(1.f+__expf(-x)); }
__device__ __forceinline__ unsigned short f2bu(float f){
    bf16 b = __float2bfloat16(f);
    return *(unsigned short*)&b;
}

__device__ __forceinline__ float ldd(const void* p, size_t i, bool f32){
    if (f32) return ((const float*)p)[i];
    else     return b2f(((const bf16*)p)[i]);
}

// ---------- probe: fp32 vs bf16 inputs ----------
__global__ void probe_kernel(const void* __restrict__ x, int* __restrict__ flag){
    if (blockIdx.x==0 && threadIdx.x==0){
        const unsigned short* h = (const unsigned short*)x;
        int wild = 0;
        for (int i=0;i<128;i++){
            int e = (h[i] >> 7) & 0xFF;
            if (e < 100 || e > 150) wild++;
        }
        flag[0] = (wild > 16) ? 1 : 0;   // 1 => fp32 inputs
    }
}

// ---------- prep: down_conv2_w -> fp32 transposed  w2t[e][o] = W[o][e] ----------
__global__ void prep_w2t_kernel(const void* __restrict__ dcw2, float* __restrict__ w2t,
                                const int* __restrict__ flag){
    bool f32 = flag[0]!=0;
    int i = blockIdx.x*256 + threadIdx.x;
    if (i < C_*C_){
        int in = i / C_, out = i % C_;
        w2t[i] = ldd(dcw2, (size_t)out*C_ + in, f32);
    }
}

// ---------- prep: small weights -> fp32 arenas (+ v_w/c_w transposes) ----------
#define PM_OLD (16384+16384+7776+512*5+96+6+3+3)
#define PM_TOTAL (PM_OLD + 262144 + 262144)
__global__ void prep_misc_kernel(const void* dcw, const void* cbw,
                                 const void* sa1w, const void* sa2w, const void* sa3w,
                                 const void* q_b, const void* k_b, const void* v_b,
                                 const void* c_b, const void* query,
                                 const void* sa1b, const void* sa2b, const void* sa3b,
                                 const void* w2, const void* w4, const void* wts,
                                 const void* v_w, const void* c_w,
                                 float* __restrict__ dwt, float* __restrict__ cbwf,
                                 float* __restrict__ saw, float* __restrict__ vecs,
                                 float* __restrict__ vwt, float* __restrict__ cwt,
                                 const int* __restrict__ flag){
    bool f32 = flag[0]!=0;
    int i = blockIdx.x*256 + threadIdx.x;
    if (i >= PM_TOTAL) return;
    if (i < 16384){ int c=i>>5, r=i&31; dwt[i] = ldd(dcw, (size_t)r*C_+c, f32); return; }
    i -= 16384;
    if (i < 16384){ cbwf[i] = ldd(cbw, i, f32); return; }
    i -= 16384;
    if (i < 7776){
        const void* s = (i<2592)? sa1w : ((i<5184)? sa2w : sa3w);
        int j = (i<2592)? i : ((i<5184)? i-2592 : i-5184);
        saw[i] = ldd(s, j, f32); return;
    }
    i -= 7776;
    if (i < 512){ vecs[VQB +i] = ldd(q_b,  i, f32); return; } i -= 512;
    if (i < 512){ vecs[VKB +i] = ldd(k_b,  i, f32); return; } i -= 512;
    if (i < 512){ vecs[VVB +i] = ldd(v_b,  i, f32); return; } i -= 512;
    if (i < 512){ vecs[VCB +i] = ldd(c_b,  i, f32); return; } i -= 512;
    if (i < 512){ vecs[VQRY+i] = ldd(query,i, f32); return; } i -= 512;
    if (i < 96){
        const void* s = (i<32)? sa1b : ((i<64)? sa2b : sa3b);
        vecs[VSAB+i] = ldd(s, i&31, f32); return;
    }
    i -= 96;
    if (i < 6){ vecs[VW2+i] = ldd(w2, i, f32); return; } i -= 6;
    if (i < 3){ vecs[VW4+i] = ldd(w4, i, f32); return; } i -= 3;
    if (i < 3){ vecs[VWTS+i] = ldd(wts, i, f32); return; } i -= 3;
    if (i < 262144){ int r=i/C_, c=i%C_; vwt[i] = ldd(v_w, (size_t)c*C_+r, f32); return; }
    i -= 262144;
    { int r=i/C_, c=i%C_; cwt[i] = ldd(c_w, (size_t)c*C_+r, f32); }
}

// ---------- T1: x -> bf16 copy (vectorized x4; staged in first half of d_out) ----------
__global__ void __launch_bounds__(256) cvt_x_kernel(const void* __restrict__ x,
                                                    bf16* __restrict__ xb,
                                                    const int* __restrict__ flag){
    bool f32 = flag[0]!=0;
    int i4 = blockIdx.x*256 + threadIdx.x;      // index of 4-elem group
    if (i4 >= XTOT/4) return;
    ushort4v u;
    if (f32){
        float4 v = ((const float4*)x)[i4];
        u[0]=f2bu(v.x); u[1]=f2bu(v.y); u[2]=f2bu(v.z); u[3]=f2bu(v.w);
    } else {
        u = ((const ushort4v*)x)[i4];
    }
    ((ushort4v*)xb)[i4] = u;
}

// ---------- K1a: qp[c] = (query . q_w[c,:] + q_b[c]) * C^-0.5 ----------
__global__ void __launch_bounds__(64) qproj1_kernel(const void* __restrict__ q_w,
        const float* __restrict__ vecs, float* __restrict__ qp,
        const int* __restrict__ flag){
    bool f32 = flag[0]!=0;
    int c = blockIdx.x;
    int lane = threadIdx.x;
    float acc = 0.f;
    #pragma unroll
    for (int i=lane;i<C_;i+=64)
        acc += vecs[VQRY+i] * ldd(q_w, (size_t)c*C_+i, f32);
    #pragma unroll
    for (int off=32; off>0; off>>=1) acc += __shfl_down(acc, off);
    if (lane==0) qp[c] = (acc + vecs[VQB+c]) * 0.044194173824159216f;   // 512^-0.5
}

// ---------- K1b: qk[c] = sum_i qp[i]*k_w[i*C+c];  qk[C] = qp . k_b ----------
__global__ void __launch_bounds__(256) qproj2_kernel(const void* __restrict__ k_w,
        const float* __restrict__ vecs, const float* __restrict__ qp,
        float* __restrict__ qk_out, const int* __restrict__ flag){
    bool f32 = flag[0]!=0;
    __shared__ float sh[256];
    int tid = threadIdx.x;
    if (blockIdx.x < 8){
        int c = blockIdx.x*64 + (tid&63);
        int isub = tid>>6;                     // 4 sub-ranges of 128 i's
        float acc = 0.f;
        for (int i=isub*128; i<isub*128+128; i++)
            acc += qp[i] * ldd(k_w, (size_t)i*C_ + c, f32);
        sh[tid] = acc;
        __syncthreads();
        if (tid < 64)
            qk_out[c] = sh[tid] + sh[tid+64] + sh[tid+128] + sh[tid+192];
    } else {
        float acc = 0.f;
        for (int i=tid;i<C_;i+=256) acc += qp[i]*vecs[VKB+i];
        sh[tid] = acc;
        __syncthreads();
        if (tid==0){
            float d=0.f;
            for (int i=0;i<256;i++) d += sh[i];
            qk_out[C_] = d;
        }
    }
}

// ---------- F1: attn logits + softmax + pooled / (mean,max part of xq) ----------
__global__ void __launch_bounds__(256) f1_kernel(const bf16* __restrict__ xb,
        const float* __restrict__ qk, const float* __restrict__ vecs,
        float* __restrict__ pooled, float* __restrict__ mm){
    int b = blockIdx.x, n = b/T_, t = b%T_;
    __shared__ float qk_s[C_];
    __shared__ float sm[HW_];
    __shared__ float red[2];
    int tid = threadIdx.x;
    for (int i=tid;i<C_;i+=256) qk_s[i] = qk[i];
    __syncthreads();
    if (tid < HW_){
        float acc = qk[C_];
        const bf16* p = xb + (size_t)n*SN_ + (size_t)t*HW_ + tid;
        for (int c=0;c<C_;c++) acc += qk_s[c]*b2f(p[(size_t)c*SC_]);
        sm[tid] = acc;
    }
    __syncthreads();
    if (tid==0){ float m=-1e30f; for(int l=0;l<HW_;l++) m=fmaxf(m,sm[l]); red[0]=m; }
    __syncthreads();
    if (tid < HW_) sm[tid] = __expf(sm[tid]-red[0]);
    __syncthreads();
    if (tid==0){ float s=0.f; for(int l=0;l<HW_;l++) s+=sm[l]; red[1]=1.f/s; }
    __syncthreads();
    if (tid < HW_) sm[tid] *= red[1];
    __syncthreads();
    float w40=vecs[VW4+0], w41=vecs[VW4+1];
    for (int c=tid;c<C_;c+=256){
        const bf16* base = xb + (size_t)n*SN_ + (size_t)c*SC_ + (size_t)t*HW_;
        float s=0.f, m=-1e30f, pl=0.f;
        for (int l4=0;l4<HW_;l4+=4){
            ushort4v u = *(const ushort4v*)(base + l4);
            #pragma unroll
            for (int k=0;k<4;k++){
                float v = u2f(u[k]);
                s += v; m = fmaxf(m,v); pl += sm[l4+k]*v;
            }
        }
        pooled[(size_t)b*C_+c] = pl;
        mm[(size_t)b*C_+c] = s*(1.f/HW_)*w40 + m*w41;
    }
}

// ---------- proj: v-proj -> c-proj -> xq -> yq (all coalesced) ----------
__global__ void __launch_bounds__(512) proj_kernel(const float* __restrict__ pooled,
        const float* __restrict__ mm, const float* __restrict__ vwt,
        const float* __restrict__ cwt, const void* __restrict__ dcw2,
        const float* __restrict__ vecs, float* __restrict__ xq,
        float* __restrict__ yq, const int* __restrict__ flag){
    bool f32 = flag[0]!=0;
    int b = blockIdx.x, c = threadIdx.x;       // 512 threads
    __shared__ float p_s[C_];
    __shared__ float pre_s[C_];
    __shared__ float xq_s[C_];
    p_s[c] = pooled[(size_t)b*C_ + c];
    __syncthreads();
    float pre = vecs[VVB+c];
    for (int i=0;i<C_;i++) pre += p_s[i]*vwt[(size_t)i*C_+c];
    pre_s[c] = pre;
    __syncthreads();
    float att = vecs[VCB+c];
    for (int i=0;i<C_;i++) att += pre_s[i]*cwt[(size_t)i*C_+c];
    float xqv = mm[(size_t)b*C_+c] + vecs[VW4+2]*att;
    xq[(size_t)b*C_+c] = xqv;
    xq_s[c] = xqv;
    __syncthreads();
    float yqv = 0.f;
    for (int i=0;i<C_;i++) yqv += xq_s[i]*ldd(dcw2, (size_t)i*C_+c, f32);
    yq[(size_t)b*C_+c] = yqv;
}

// ---------- corr2g: gate logits + sigmoid gate, one (b,j) per block ----------
// grid (B_, 6) x 256 thr. g[(b*6+j)*HW + l] = w2j*(sigm(w2j*dot)-0.5) or 0 if invalid.
__global__ void __launch_bounds__(256) corr2g_kernel(const bf16* __restrict__ xb,
        const float* __restrict__ yq, const float* __restrict__ vecs,
        float* __restrict__ g){
    const int offs[6] = {-3,-2,-1,1,2,3};
    int b = blockIdx.x, j = blockIdx.y;
    int n = b/T_, t = b%T_;
    int tj = t + offs[j];
    int tid = threadIdx.x;
    if (tj < 0 || tj >= T_){
        if (tid < HW_) g[((size_t)b*6+j)*HW_ + tid] = 0.f;
        return;
    }
    __shared__ float yq_s[C_];
    for (int i=tid;i<C_;i+=256) yq_s[i] = yq[(size_t)b*C_+i];
    __syncthreads();
    if (tid < HW_){
        float acc = 0.f;
        const bf16* p = xb + (size_t)n*SN_ + (size_t)tj*HW_ + tid;
        for (int e=0;e<C_;e++) acc += yq_s[e]*b2f(p[(size_t)e*SC_]);
        float w2j = vecs[VW2+j];
        g[((size_t)b*6+j)*HW_ + tid] = w2j*(sigm(w2j*acc)-0.5f);
    }
}

// ---------- corr2z: z[b][e] = sum_{j,l} g[b][j][l]*xb[n,e,tj,l] ----------
// grid (B_) x 512 thr. Wave-per-e: 49 lanes read a contiguous 392B row (coalesced),
// shuffle-reduce across the wave.
__global__ void __launch_bounds__(512) corr2z_kernel(const bf16* __restrict__ xb,
        const float* __restrict__ g, float* __restrict__ zbuf){
    const int offs[6] = {-3,-2,-1,1,2,3};
    int b = blockIdx.x, n = b/T_, t = b%T_;
    int tid = threadIdx.x;
    __shared__ float g_s[6*HW_];
    __shared__ float z_s[C_];
    for (int i=tid;i<6*HW_;i+=512) g_s[i] = g[(size_t)b*6*HW_ + i];
    __syncthreads();
    int wave = tid>>6, lane = tid&63;
    bool act = lane < HW_/4;                 // 49 active lanes
    for (int e=wave; e<C_; e+=8){
        float acc = 0.f;
        const bf16* er = xb + (size_t)n*SN_ + (size_t)e*SC_;
        #pragma unroll
        for (int j=0;j<6;j++){
            int tj = t + offs[j];
            if (tj<0 || tj>=T_) continue;
            if (act){
                ushort4v u = *(const ushort4v*)(er + (size_t)tj*HW_ + lane*4);
                const float* gp = &g_s[j*HW_ + lane*4];
                acc += gp[0]*u2f(u[0]) + gp[1]*u2f(u[1])
                     + gp[2]*u2f(u[2]) + gp[3]*u2f(u[3]);
            }
        }
        #pragma unroll
        for (int off=32; off>0; off>>=1) acc += __shfl_down(acc, off);
        if (lane==0) z_s[e] = acc;
    }
    __syncthreads();
    if (tid < C_) zbuf[(size_t)b*C_ + tid] = z_s[tid];
}

// ---------- corr2f: feat[b][c] = sum_e w2t[e][c]*z[b][e] ----------
// grid (B_, 4) x 128 thr.
__global__ void __launch_bounds__(128) corr2f_kernel(const float* __restrict__ zbuf,
        const float* __restrict__ w2t, float* __restrict__ feat){
    int b = blockIdx.x, c0 = blockIdx.y*128;
    int tid = threadIdx.x;
    __shared__ float z_s[C_];
    for (int i=tid;i<C_;i+=128) z_s[i] = zbuf[(size_t)b*C_+i];
    __syncthreads();
    int c = c0 + tid;
    float acc = 0.f;
    for (int e=0;e<C_;e++) acc += w2t[(size_t)e*C_+c]*z_s[e];
    feat[(size_t)b*C_+c] = acc;
}

// ---------- xdown: x_down = down_conv_w @ x (bf16 out) ----------
__global__ void __launch_bounds__(256) xdown_kernel(const bf16* __restrict__ xb,
                                                    const float* __restrict__ dwt,
                                                    bf16* __restrict__ xd){
    int b = blockIdx.x, n = b/T_, t = b%T_;
    int hw = threadIdx.x;
    int hwc = hw < HW_ ? hw : HW_-1;
    float acc[RC_];
    #pragma unroll
    for (int r=0;r<RC_;r++) acc[r]=0.f;
    const bf16* xp = xb + (size_t)n*SN_ + (size_t)t*HW_ + hwc;
    for (int c=0;c<C_;c++){
        float xv = b2f(xp[(size_t)c*SC_]);
        const float* wr = dwt + c*RC_;         // wave-uniform
        #pragma unroll
        for (int r=0;r<RC_;r++) acc[r] += wr[r]*xv;
    }
    if (hw < HW_){
        #pragma unroll
        for (int r=0;r<RC_;r++)
            xd[(((size_t)n*RC_ + r)*T_ + t)*HW_ + hw] = __float2bfloat16(acc[r]);
    }
}

// ---------- dwconv: padded-tile version, one (n,r,t) per block ----------
#define TPAD 21
#define TROW 20
#define TFRM (TROW*TPAD)   // 420
__global__ void __launch_bounds__(256) dwconv_kernel(const bf16* __restrict__ xd,
        const float* __restrict__ saw, const float* __restrict__ vecs,
        float* __restrict__ aggs){
    int nr = blockIdx.x;            // n*RC_+r
    int t  = blockIdx.y;
    int r  = nr % RC_;
    __shared__ float tile[9*TFRM];
    __shared__ float wsm[3][81];
    int tid = threadIdx.x;          // 256
    for (int i=tid;i<9*TFRM;i+=256) tile[i] = 0.f;
    if (tid < 81){
        wsm[0][tid]=saw[       r*81+tid];
        wsm[1][tid]=saw[2592 + r*81+tid];
        wsm[2][tid]=saw[5184 + r*81+tid];
    }
    __syncthreads();
    const bf16* base = xd + (size_t)nr*T_*HW_;
    for (int i=tid;i<9*HW_;i+=256){
        int kt = i/HW_, hw = i - kt*HW_;
        int tg = t - 4 + kt;
        if (tg>=0 && tg<T_){
            int h = hw/W_, w = hw - h*W_;
            tile[kt*TFRM + (h+3)*TPAD + (w+3)] = b2f(base[(size_t)tg*HW_ + hw]);
        }
    }
    __syncthreads();
    if (tid < HW_){
        int h = tid/W_, w = tid - h*W_;
        float w0=vecs[VWTS+0], w1=vecs[VWTS+1], w2v=vecs[VWTS+2];
        float cbias = w0*vecs[VSAB+r] + w1*vecs[VSAB+32+r] + w2v*vecs[VSAB+64+r];
        float bacc[3];
        #pragma unroll
        for (int br=0;br<3;br++){
            int d = br+1;
            float s = 0.f;
            #pragma unroll
            for (int kt=0;kt<9;kt++){
                const float* tb = &tile[kt*TFRM + (h+3-d)*TPAD + (w+3-d)];
                const float* wp = &wsm[br][kt*9];
                s += wp[0]*tb[0]          + wp[1]*tb[d]          + wp[2]*tb[2*d]
                   + wp[3]*tb[d*TPAD]     + wp[4]*tb[d*TPAD+d]   + wp[5]*tb[d*TPAD+2*d]
                   + wp[6]*tb[2*d*TPAD]   + wp[7]*tb[2*d*TPAD+d] + wp[8]*tb[2*d*TPAD+2*d];
            }
            bacc[br] = s;
        }
        float acc = cbias + w0*bacc[0] + w1*bacc[1] + w2v*bacc[2];
        aggs[(size_t)nr*T_*HW_ + (size_t)t*HW_ + tid] = acc;
    }
}

// ---------- final: conv_back (reg-resident agg) + gate * feat -> fp32 out ----------
__global__ void __launch_bounds__(256) final_kernel(const float* __restrict__ aggs,
                                                    const float* __restrict__ cbwf,
                                                    const float* __restrict__ feat,
                                                    float* __restrict__ out){
    int b = blockIdx.x, n = b/T_, t = b%T_;
    int c0 = blockIdx.y*128;
    int hw = threadIdx.x;
    if (hw >= HW_) return;
    float ra[RC_];
    #pragma unroll
    for (int r=0;r<RC_;r++)
        ra[r] = aggs[(((size_t)n*RC_+r)*T_ + t)*HW_ + hw];
    const float* fb = feat + (size_t)b*C_;
    for (int ci=0;ci<128;ci++){
        int c = c0+ci;
        const float* wr = cbwf + c*RC_;    // wave-uniform
        float a = 0.f;
        #pragma unroll
        for (int r=0;r<RC_;r++) a += wr[r]*ra[r];
        out[(((size_t)n*C_+c)*T_ + t)*HW_ + hw] = fb[c]*(sigm(a)-0.5f);
    }
}

extern "C" void kernel_launch(void* const* d_in, const int* in_sizes, int n_in,
                              void* d_out, int out_size, void* d_ws, size_t ws_size,
                              hipStream_t stream){
    const void* x      = d_in[0];
    const void* dcw2   = d_in[1];
    const void* dcw    = d_in[2];
    const void* cbw    = d_in[3];
    const void* w2     = d_in[4];
    const void* w4     = d_in[5];
    const void* wts    = d_in[6];
    const void* query  = d_in[7];
    const void* q_w    = d_in[8];
    const void* q_b    = d_in[9];
    const void* k_w    = d_in[10];
    const void* k_b    = d_in[11];
    const void* v_w    = d_in[12];
    const void* v_b    = d_in[13];
    const void* c_w    = d_in[14];
    const void* c_b    = d_in[15];
    const void* sa1w   = d_in[16];
    const void* sa1b   = d_in[17];
    const void* sa2w   = d_in[18];
    const void* sa2b   = d_in[19];
    const void* sa3w   = d_in[20];
    const void* sa3b   = d_in[21];
    float* out = (float*)d_out;

    // workspace layout — ~12.5 MB (+4KB qp scratch)
    float* ws    = (float*)d_ws;
    int*   flag  = (int*)ws;               // 16
    float* qk    = ws + 16;                // 1024
    float* qp    = qk + 1024;              // 1024 (uses 512)
    float* pooled= qp + 1024;              // 98304
    float* mm    = pooled + 98304;         // 98304
    float* xq    = mm + 98304;             // 98304
    float* yq    = xq + 98304;             // 98304
    float* feat  = yq + 98304;             // 98304
    float* w2t   = feat + 98304;           // 262144
    float* vwt   = w2t + 262144;           // 262144
    float* cwt   = vwt + 262144;           // 262144
    float* dwt   = cwt + 262144;           // 16384
    float* cbwf  = dwt + 16384;            // 16384
    float* saw   = cbwf + 16384;           // 7936 (uses 7776)
    float* vecs  = saw + 7936;             // 2720
    float* aggs  = vecs + VECS_TOTAL;      // 1204224 fp32
    bf16*  xd    = (bf16*)(aggs + 1204224);// 1204224 bf16
    // corr2 scratch aliases aggs: g (225792 fp32) + zbuf (98304 fp32) are fully
    // consumed by corr2f BEFORE dwconv_kernel writes aggs (stream-ordered).
    float* g     = aggs;                   // 225792
    float* zbuf  = aggs + 225792;          // 98304  (total 324096 < 1204224)
    // xb staged in the FIRST HALF of d_out (38.5 MB of 77 MB); fully consumed
    // by f1/corr2*/xdown before final_kernel overwrites all of d_out.
    bf16*  xb    = (bf16*)d_out;

    probe_kernel<<<1, 64, 0, stream>>>(x, flag);
    prep_w2t_kernel<<<(C_*C_+255)/256, 256, 0, stream>>>(dcw2, w2t, flag);
    prep_misc_kernel<<<(PM_TOTAL+255)/256, 256, 0, stream>>>(
        dcw, cbw, sa1w, sa2w, sa3w, q_b, k_b, v_b, c_b, query,
        sa1b, sa2b, sa3b, w2, w4, wts, v_w, c_w,
        dwt, cbwf, saw, vecs, vwt, cwt, flag);
    cvt_x_kernel<<<(XTOT/4+255)/256, 256, 0, stream>>>(x, xb, flag);

    qproj1_kernel<<<C_, 64, 0, stream>>>(q_w, vecs, qp, flag);
    qproj2_kernel<<<9, 256, 0, stream>>>(k_w, vecs, qp, qk, flag);
    f1_kernel<<<B_, 256, 0, stream>>>(xb, qk, vecs, pooled, mm);
    proj_kernel<<<B_, C_, 0, stream>>>(pooled, mm, vwt, cwt, dcw2, vecs, xq, yq, flag);

    corr2g_kernel<<<dim3(B_, 6), 256, 0, stream>>>(xb, yq, vecs, g);
    corr2z_kernel<<<B_, 512, 0, stream>>>(xb, g, zbuf);
    corr2f_kernel<<<dim3(B_, 4), 128, 0, stream>>>(zbuf, w2t, feat);

    xdown_kernel<<<B_, 256, 0, stream>>>(xb, dwt, xd);
    dwconv_kernel<<<dim3(N_*RC_, T_), 256, 0, stream>>>(xd, saw, vecs, aggs);
    final_kernel<<<dim3(B_, 4), 256, 0, stream>>>(aggs, cbwf, feat, out);
}

// Round 3
// 721.881 us; speedup vs baseline: 1.1080x; 1.1080x over previous
//
#include <hip/hip_runtime.h>
#include <hip/hip_bf16.h>

using bf16 = __hip_bfloat16;
typedef __attribute__((ext_vector_type(4))) unsigned short ushort4v;

#define N_  2
#define C_  512
#define T_  96
#define H_  14
#define W_  14
#define HW_ 196
#define RC_ 32
#define B_  (N_*T_)    // 192
#define SC_ (T_*HW_)   // 18816 elems per channel (input layout)
#define XTOT (N_*C_*T_*HW_)  // 19267584

// fp32 vec arena offsets
#define VQB   0
#define VKB   512
#define VVB   1024
#define VCB   1536
#define VQRY  2048
#define VSAB  2560   // 96 (3x32)
#define VW2   2688   // 6
#define VW4   2696   // 3
#define VWTS  2700   // 3
#define VECS_TOTAL 2720

__device__ __forceinline__ float b2f(bf16 v){ return __bfloat162float(v); }
__device__ __forceinline__ float u2f(unsigned short u){ return __uint_as_float(((unsigned)u)<<16); }
__device__ __forceinline__ float sigm(float x){ return 1.f/(1.f+__expf(-x)); }
__device__ __forceinline__ unsigned short f2bu(float f){
    bf16 b = __float2bfloat16(f);
    return *(unsigned short*)&b;
}

__device__ __forceinline__ float ldd(const void* p, size_t i, bool f32){
    if (f32) return ((const float*)p)[i];
    else     return b2f(((const bf16*)p)[i]);
}

// ---------- probe: fp32 vs bf16 inputs ----------
__global__ void probe_kernel(const void* __restrict__ x, int* __restrict__ flag){
    if (blockIdx.x==0 && threadIdx.x==0){
        const unsigned short* h = (const unsigned short*)x;
        int wild = 0;
        for (int i=0;i<128;i++){
            int e = (h[i] >> 7) & 0xFF;
            if (e < 100 || e > 150) wild++;
        }
        flag[0] = (wild > 16) ? 1 : 0;   // 1 => fp32 inputs
    }
}

// ---------- prep: down_conv2_w -> fp32 transposed  w2t[e][o] = W[o][e] ----------
__global__ void prep_w2t_kernel(const void* __restrict__ dcw2, float* __restrict__ w2t,
                                const int* __restrict__ flag){
    bool f32 = flag[0]!=0;
    int i = blockIdx.x*256 + threadIdx.x;
    if (i < C_*C_){
        int in = i / C_, out = i % C_;
        w2t[i] = ldd(dcw2, (size_t)out*C_ + in, f32);
    }
}

// ---------- prep: small weights -> fp32 arenas (+ v_w/c_w transposes) ----------
#define PM_OLD (16384+16384+7776+512*5+96+6+3+3)
#define PM_TOTAL (PM_OLD + 262144 + 262144)
__global__ void prep_misc_kernel(const void* dcw, const void* cbw,
                                 const void* sa1w, const void* sa2w, const void* sa3w,
                                 const void* q_b, const void* k_b, const void* v_b,
                                 const void* c_b, const void* query,
                                 const void* sa1b, const void* sa2b, const void* sa3b,
                                 const void* w2, const void* w4, const void* wts,
                                 const void* v_w, const void* c_w,
                                 float* __restrict__ dwt, float* __restrict__ cbwf,
                                 float* __restrict__ saw, float* __restrict__ vecs,
                                 float* __restrict__ vwt, float* __restrict__ cwt,
                                 const int* __restrict__ flag){
    bool f32 = flag[0]!=0;
    int i = blockIdx.x*256 + threadIdx.x;
    if (i >= PM_TOTAL) return;
    if (i < 16384){ int c=i>>5, r=i&31; dwt[i] = ldd(dcw, (size_t)r*C_+c, f32); return; }
    i -= 16384;
    if (i < 16384){ cbwf[i] = ldd(cbw, i, f32); return; }
    i -= 16384;
    if (i < 7776){
        const void* s = (i<2592)? sa1w : ((i<5184)? sa2w : sa3w);
        int j = (i<2592)? i : ((i<5184)? i-2592 : i-5184);
        saw[i] = ldd(s, j, f32); return;
    }
    i -= 7776;
    if (i < 512){ vecs[VQB +i] = ldd(q_b,  i, f32); return; } i -= 512;
    if (i < 512){ vecs[VKB +i] = ldd(k_b,  i, f32); return; } i -= 512;
    if (i < 512){ vecs[VVB +i] = ldd(v_b,  i, f32); return; } i -= 512;
    if (i < 512){ vecs[VCB +i] = ldd(c_b,  i, f32); return; } i -= 512;
    if (i < 512){ vecs[VQRY+i] = ldd(query,i, f32); return; } i -= 512;
    if (i < 96){
        const void* s = (i<32)? sa1b : ((i<64)? sa2b : sa3b);
        vecs[VSAB+i] = ldd(s, i&31, f32); return;
    }
    i -= 96;
    if (i < 6){ vecs[VW2+i] = ldd(w2, i, f32); return; } i -= 6;
    if (i < 3){ vecs[VW4+i] = ldd(w4, i, f32); return; } i -= 3;
    if (i < 3){ vecs[VWTS+i] = ldd(wts, i, f32); return; } i -= 3;
    if (i < 262144){ int r=i/C_, c=i%C_; vwt[i] = ldd(v_w, (size_t)c*C_+r, f32); return; }
    i -= 262144;
    { int r=i/C_, c=i%C_; cwt[i] = ldd(c_w, (size_t)c*C_+r, f32); }
}

// ---------- cvt_tr: x (n,c,t,l) -> xt (n,t,l,c) bf16, LDS-tiled transpose ----------
#define TCH 128
__global__ void __launch_bounds__(256) cvt_tr_kernel(const void* __restrict__ x,
                                                     bf16* __restrict__ xt,
                                                     const int* __restrict__ flag){
    bool f32 = flag[0]!=0;
    int bt = blockIdx.x;               // n*T+t
    int n = bt / T_, t = bt % T_;
    int c0 = blockIdx.y * TCH;
    __shared__ bf16 tile[TCH*197];     // +1 elem pad per row
    int tid = threadIdx.x;
    const size_t ibase = (((size_t)n*C_ + c0)*T_ + t)*HW_;
    for (int i=tid; i<TCH*HW_; i+=256){
        int cr = i / HW_, l = i - cr*HW_;
        tile[cr*197 + l] = __float2bfloat16(ldd(x, ibase + (size_t)cr*SC_ + l, f32));
    }
    __syncthreads();
    bf16* obase = xt + (size_t)bt*HW_*C_ + c0;
    for (int i=tid; i<HW_*TCH; i+=256){
        int l = i >> 7, cl = i & 127;
        obase[(size_t)l*C_ + cl] = tile[cl*197 + l];
    }
}

// ---------- K1a: qp[c] = (query . q_w[c,:] + q_b[c]) * C^-0.5 ----------
__global__ void __launch_bounds__(64) qproj1_kernel(const void* __restrict__ q_w,
        const float* __restrict__ vecs, float* __restrict__ qp,
        const int* __restrict__ flag){
    bool f32 = flag[0]!=0;
    int c = blockIdx.x;
    int lane = threadIdx.x;
    float acc = 0.f;
    #pragma unroll
    for (int i=lane;i<C_;i+=64)
        acc += vecs[VQRY+i] * ldd(q_w, (size_t)c*C_+i, f32);
    #pragma unroll
    for (int off=32; off>0; off>>=1) acc += __shfl_down(acc, off);
    if (lane==0) qp[c] = (acc + vecs[VQB+c]) * 0.044194173824159216f;   // 512^-0.5
}

// ---------- K1b: qk[c] = sum_i qp[i]*k_w[i*C+c];  qk[C] = qp . k_b ----------
__global__ void __launch_bounds__(256) qproj2_kernel(const void* __restrict__ k_w,
        const float* __restrict__ vecs, const float* __restrict__ qp,
        float* __restrict__ qk_out, const int* __restrict__ flag){
    bool f32 = flag[0]!=0;
    __shared__ float sh[256];
    int tid = threadIdx.x;
    if (blockIdx.x < 8){
        int c = blockIdx.x*64 + (tid&63);
        int isub = tid>>6;
        float acc = 0.f;
        for (int i=isub*128; i<isub*128+128; i++)
            acc += qp[i] * ldd(k_w, (size_t)i*C_ + c, f32);
        sh[tid] = acc;
        __syncthreads();
        if (tid < 64)
            qk_out[c] = sh[tid] + sh[tid+64] + sh[tid+128] + sh[tid+192];
    } else {
        float acc = 0.f;
        for (int i=tid;i<C_;i+=256) acc += qp[i]*vecs[VKB+i];
        sh[tid] = acc;
        __syncthreads();
        if (tid==0){
            float d=0.f;
            for (int i=0;i<256;i++) d += sh[i];
            qk_out[C_] = d;
        }
    }
}

// ---------- F1: logits (wave-per-l, coalesced) + softmax + pooled/mm (thread-per-c) ----------
__global__ void __launch_bounds__(512) f1_kernel(const bf16* __restrict__ xt,
        const float* __restrict__ qk, const float* __restrict__ vecs,
        float* __restrict__ pooled, float* __restrict__ mm){
    int b = blockIdx.x;
    __shared__ float sm[HW_];
    __shared__ float red[2];
    int tid = threadIdx.x, wave = tid>>6, lane = tid&63;
    float qkr[8];
    #pragma unroll
    for (int k=0;k<4;k++){ qkr[k] = qk[lane*4+k]; qkr[4+k] = qk[256+lane*4+k]; }
    float qkC = qk[C_];
    const bf16* fbase = xt + (size_t)b*HW_*C_;
    for (int l=wave; l<HW_; l+=8){
        const bf16* row = fbase + (size_t)l*C_;
        ushort4v u1 = *(const ushort4v*)(row + lane*4);
        ushort4v u2 = *(const ushort4v*)(row + 256 + lane*4);
        float a = 0.f;
        #pragma unroll
        for (int k=0;k<4;k++) a += qkr[k]*u2f(u1[k]) + qkr[4+k]*u2f(u2[k]);
        #pragma unroll
        for (int off=32; off>0; off>>=1) a += __shfl_down(a, off);
        if (lane==0) sm[l] = a + qkC;
    }
    __syncthreads();
    if (tid < 64){
        float m = -1e30f;
        for (int l=tid; l<HW_; l+=64) m = fmaxf(m, sm[l]);
        #pragma unroll
        for (int off=32; off>0; off>>=1) m = fmaxf(m, __shfl_down(m, off));
        if (tid==0) red[0] = m;
    }
    __syncthreads();
    if (tid < HW_) sm[tid] = __expf(sm[tid]-red[0]);
    __syncthreads();
    if (tid < 64){
        float s = 0.f;
        for (int l=tid; l<HW_; l+=64) s += sm[l];
        #pragma unroll
        for (int off=32; off>0; off>>=1) s += __shfl_down(s, off);
        if (tid==0) red[1] = 1.f/s;
    }
    __syncthreads();
    if (tid < HW_) sm[tid] *= red[1];
    __syncthreads();
    float w40=vecs[VW4+0], w41=vecs[VW4+1];
    int c = tid;
    const bf16* p = fbase + c;
    float s=0.f, m=-1e30f, pl=0.f;
    for (int l=0;l<HW_;l++){
        float v = u2f(*(const unsigned short*)(p + (size_t)l*C_));
        s += v; m = fmaxf(m, v); pl += sm[l]*v;
    }
    pooled[(size_t)b*C_+c] = pl;
    mm[(size_t)b*C_+c] = s*(1.f/HW_)*w40 + m*w41;
}

// ---------- proj: v-proj -> c-proj -> xq -> yq (all coalesced) ----------
__global__ void __launch_bounds__(512) proj_kernel(const float* __restrict__ pooled,
        const float* __restrict__ mm, const float* __restrict__ vwt,
        const float* __restrict__ cwt, const void* __restrict__ dcw2,
        const float* __restrict__ vecs, float* __restrict__ xq,
        float* __restrict__ yq, const int* __restrict__ flag){
    bool f32 = flag[0]!=0;
    int b = blockIdx.x, c = threadIdx.x;       // 512 threads
    __shared__ float p_s[C_];
    __shared__ float pre_s[C_];
    __shared__ float xq_s[C_];
    p_s[c] = pooled[(size_t)b*C_ + c];
    __syncthreads();
    float pre = vecs[VVB+c];
    for (int i=0;i<C_;i++) pre += p_s[i]*vwt[(size_t)i*C_+c];
    pre_s[c] = pre;
    __syncthreads();
    float att = vecs[VCB+c];
    for (int i=0;i<C_;i++) att += pre_s[i]*cwt[(size_t)i*C_+c];
    float xqv = mm[(size_t)b*C_+c] + vecs[VW4+2]*att;
    xq[(size_t)b*C_+c] = xqv;
    xq_s[c] = xqv;
    __syncthreads();
    float yqv = 0.f;
    for (int i=0;i<C_;i++) yqv += xq_s[i]*ldd(dcw2, (size_t)i*C_+c, f32);
    yq[(size_t)b*C_+c] = yqv;
}

// ---------- corr2g: gates, wave-per-l over contiguous c (xt layout) ----------
__global__ void __launch_bounds__(256) corr2g_kernel(const bf16* __restrict__ xt,
        const float* __restrict__ yq, const float* __restrict__ vecs,
        float* __restrict__ g){
    const int offs[6] = {-3,-2,-1,1,2,3};
    int b = blockIdx.x, j = blockIdx.y;
    int n = b/T_, t = b%T_;
    int tj = t + offs[j];
    int tid = threadIdx.x, wave = tid>>6, lane = tid&63;
    if (tj < 0 || tj >= T_){
        if (tid < HW_) g[((size_t)b*6+j)*HW_ + tid] = 0.f;
        return;
    }
    float yqr[8];
    const float* yb = yq + (size_t)b*C_;
    #pragma unroll
    for (int k=0;k<4;k++){ yqr[k]=yb[lane*4+k]; yqr[4+k]=yb[256+lane*4+k]; }
    float w2j = vecs[VW2+j];
    const bf16* fbase = xt + ((size_t)n*T_ + tj)*HW_*C_;
    for (int l=wave; l<HW_; l+=4){
        const bf16* row = fbase + (size_t)l*C_;
        ushort4v u1 = *(const ushort4v*)(row + lane*4);
        ushort4v u2 = *(const ushort4v*)(row + 256 + lane*4);
        float a=0.f;
        #pragma unroll
        for (int k=0;k<4;k++) a += yqr[k]*u2f(u1[k]) + yqr[4+k]*u2f(u2[k]);
        #pragma unroll
        for (int off=32; off>0; off>>=1) a += __shfl_down(a, off);
        if (lane==0) g[((size_t)b*6+j)*HW_ + l] = w2j*(sigm(w2j*a)-0.5f);
    }
}

// ---------- corr2z: z[b][e] = sum_{j,l} g*xt[tj][l][e], coalesced ushort4 over e ----------
__global__ void __launch_bounds__(512) corr2z_kernel(const bf16* __restrict__ xt,
        const float* __restrict__ g, float* __restrict__ zbuf){
    const int offs[6] = {-3,-2,-1,1,2,3};
    int b = blockIdx.x, n=b/T_, t=b%T_;
    int tid = threadIdx.x;
    __shared__ float g_s[6*HW_];
    __shared__ float zred[4][C_];
    for (int i=tid;i<6*HW_;i+=512) g_s[i] = g[(size_t)b*6*HW_ + i];
    __syncthreads();
    int grp = tid>>7, te = tid&127;
    float a0=0.f,a1=0.f,a2=0.f,a3=0.f;
    #pragma unroll
    for (int j=0;j<6;j++){
        int tj = t+offs[j];
        if (tj<0||tj>=T_) continue;
        const bf16* fbase = xt + ((size_t)n*T_+tj)*HW_*C_ + te*4;
        const float* gj = g_s + j*HW_;
        for (int l=grp; l<HW_; l+=4){
            float gv = gj[l];
            ushort4v u = *(const ushort4v*)(fbase + (size_t)l*C_);
            a0 += gv*u2f(u[0]); a1 += gv*u2f(u[1]);
            a2 += gv*u2f(u[2]); a3 += gv*u2f(u[3]);
        }
    }
    zred[grp][te*4+0]=a0; zred[grp][te*4+1]=a1;
    zred[grp][te*4+2]=a2; zred[grp][te*4+3]=a3;
    __syncthreads();
    int e = tid;
    zbuf[(size_t)b*C_+e] = zred[0][e]+zred[1][e]+zred[2][e]+zred[3][e];
}

// ---------- corr2f: feat[b][c] = sum_e w2t[e][c]*z[b][e] ----------
__global__ void __launch_bounds__(128) corr2f_kernel(const float* __restrict__ zbuf,
        const float* __restrict__ w2t, float* __restrict__ feat){
    int b = blockIdx.x, c0 = blockIdx.y*128;
    int tid = threadIdx.x;
    __shared__ float z_s[C_];
    for (int i=tid;i<C_;i+=128) z_s[i] = zbuf[(size_t)b*C_+i];
    __syncthreads();
    int c = c0 + tid;
    float acc = 0.f;
    for (int e=0;e<C_;e++) acc += w2t[(size_t)e*C_+c]*z_s[e];
    feat[(size_t)b*C_+c] = acc;
}

// ---------- xdown: x_down = down_conv_w @ x, LDS row-stage (xt layout) ----------
// grid (B_, 25): block covers l0=by*8..+7 (last 4). 256 thr: r=tid>>3, ls=tid&7.
__global__ void __launch_bounds__(256) xdown_kernel(const bf16* __restrict__ xt,
                                                    const float* __restrict__ dwt,
                                                    bf16* __restrict__ xd){
    int b = blockIdx.x, n=b/T_, t=b%T_;
    int l0 = blockIdx.y*8;
    int nl = HW_ - l0; if (nl > 8) nl = 8;
    __shared__ bf16 xs[8*C_];
    int tid = threadIdx.x;
    const bf16* fbase = xt + (size_t)b*HW_*C_ + (size_t)l0*C_;
    for (int i=tid; i<nl*C_; i+=256) xs[i] = fbase[i];
    __syncthreads();
    int r = tid>>3, ls = tid&7;
    if (ls < nl){
        float acc = 0.f;
        for (int c=0;c<C_;c++)
            acc += dwt[c*RC_ + r] * b2f(xs[ls*C_ + c]);
        xd[(((size_t)n*RC_+r)*T_ + t)*HW_ + l0 + ls] = __float2bfloat16(acc);
    }
}

// ---------- dwconv: padded-tile version, one (n,r,t) per block ----------
#define TPAD 21
#define TROW 20
#define TFRM (TROW*TPAD)   // 420
__global__ void __launch_bounds__(256) dwconv_kernel(const bf16* __restrict__ xd,
        const float* __restrict__ saw, const float* __restrict__ vecs,
        float* __restrict__ aggs){
    int nr = blockIdx.x;            // n*RC_+r
    int t  = blockIdx.y;
    int r  = nr % RC_;
    __shared__ float tile[9*TFRM];
    __shared__ float wsm[3][81];
    int tid = threadIdx.x;          // 256
    for (int i=tid;i<9*TFRM;i+=256) tile[i] = 0.f;
    if (tid < 81){
        wsm[0][tid]=saw[       r*81+tid];
        wsm[1][tid]=saw[2592 + r*81+tid];
        wsm[2][tid]=saw[5184 + r*81+tid];
    }
    __syncthreads();
    const bf16* base = xd + (size_t)nr*T_*HW_;
    for (int i=tid;i<9*HW_;i+=256){
        int kt = i/HW_, hw = i - kt*HW_;
        int tg = t - 4 + kt;
        if (tg>=0 && tg<T_){
            int h = hw/W_, w = hw - h*W_;
            tile[kt*TFRM + (h+3)*TPAD + (w+3)] = b2f(base[(size_t)tg*HW_ + hw]);
        }
    }
    __syncthreads();
    if (tid < HW_){
        int h = tid/W_, w = tid - h*W_;
        float w0=vecs[VWTS+0], w1=vecs[VWTS+1], w2v=vecs[VWTS+2];
        float cbias = w0*vecs[VSAB+r] + w1*vecs[VSAB+32+r] + w2v*vecs[VSAB+64+r];
        float bacc[3];
        #pragma unroll
        for (int br=0;br<3;br++){
            int d = br+1;
            float s = 0.f;
            #pragma unroll
            for (int kt=0;kt<9;kt++){
                const float* tb = &tile[kt*TFRM + (h+3-d)*TPAD + (w+3-d)];
                const float* wp = &wsm[br][kt*9];
                s += wp[0]*tb[0]          + wp[1]*tb[d]          + wp[2]*tb[2*d]
                   + wp[3]*tb[d*TPAD]     + wp[4]*tb[d*TPAD+d]   + wp[5]*tb[d*TPAD+2*d]
                   + wp[6]*tb[2*d*TPAD]   + wp[7]*tb[2*d*TPAD+d] + wp[8]*tb[2*d*TPAD+2*d];
            }
            bacc[br] = s;
        }
        float acc = cbias + w0*bacc[0] + w1*bacc[1] + w2v*bacc[2];
        aggs[(size_t)nr*T_*HW_ + (size_t)t*HW_ + tid] = acc;
    }
}

// ---------- final: conv_back (reg-resident agg) + gate * feat -> fp32 out ----------
__global__ void __launch_bounds__(256) final_kernel(const float* __restrict__ aggs,
                                                    const float* __restrict__ cbwf,
                                                    const float* __restrict__ feat,
                                                    float* __restrict__ out){
    int b = blockIdx.x, n = b/T_, t = b%T_;
    int c0 = blockIdx.y*128;
    int hw = threadIdx.x;
    if (hw >= HW_) return;
    float ra[RC_];
    #pragma unroll
    for (int r=0;r<RC_;r++)
        ra[r] = aggs[(((size_t)n*RC_+r)*T_ + t)*HW_ + hw];
    const float* fb = feat + (size_t)b*C_;
    for (int ci=0;ci<128;ci++){
        int c = c0+ci;
        const float* wr = cbwf + c*RC_;    // wave-uniform
        float a = 0.f;
        #pragma unroll
        for (int r=0;r<RC_;r++) a += wr[r]*ra[r];
        out[(((size_t)n*C_+c)*T_ + t)*HW_ + hw] = fb[c]*(sigm(a)-0.5f);
    }
}

extern "C" void kernel_launch(void* const* d_in, const int* in_sizes, int n_in,
                              void* d_out, int out_size, void* d_ws, size_t ws_size,
                              hipStream_t stream){
    const void* x      = d_in[0];
    const void* dcw2   = d_in[1];
    const void* dcw    = d_in[2];
    const void* cbw    = d_in[3];
    const void* w2     = d_in[4];
    const void* w4     = d_in[5];
    const void* wts    = d_in[6];
    const void* query  = d_in[7];
    const void* q_w    = d_in[8];
    const void* q_b    = d_in[9];
    const void* k_w    = d_in[10];
    const void* k_b    = d_in[11];
    const void* v_w    = d_in[12];
    const void* v_b    = d_in[13];
    const void* c_w    = d_in[14];
    const void* c_b    = d_in[15];
    const void* sa1w   = d_in[16];
    const void* sa1b   = d_in[17];
    const void* sa2w   = d_in[18];
    const void* sa2b   = d_in[19];
    const void* sa3w   = d_in[20];
    const void* sa3b   = d_in[21];
    float* out = (float*)d_out;

    // workspace layout — ~12.5 MB
    float* ws    = (float*)d_ws;
    int*   flag  = (int*)ws;               // 16
    float* qk    = ws + 16;                // 1024
    float* qp    = qk + 1024;              // 1024 (uses 512)
    float* pooled= qp + 1024;              // 98304
    float* mm    = pooled + 98304;         // 98304
    float* xq    = mm + 98304;             // 98304
    float* yq    = xq + 98304;             // 98304
    float* feat  = yq + 98304;             // 98304
    float* w2t   = feat + 98304;           // 262144
    float* vwt   = w2t + 262144;           // 262144
    float* cwt   = vwt + 262144;           // 262144
    float* dwt   = cwt + 262144;           // 16384
    float* cbwf  = dwt + 16384;            // 16384
    float* saw   = cbwf + 16384;           // 7936 (uses 7776)
    float* vecs  = saw + 7936;             // 2720
    float* aggs  = vecs + VECS_TOTAL;      // 1204224 fp32
    bf16*  xd    = (bf16*)(aggs + 1204224);// 1204224 bf16
    // corr2 scratch aliases aggs (consumed before dwconv writes aggs):
    float* g     = aggs;                   // 225792
    float* zbuf  = aggs + 225792;          // 98304
    // xt (channel-last bf16 x) staged in first half of d_out (38.5 MB of 77 MB);
    // fully consumed by f1/corr2*/xdown before final_kernel overwrites d_out.
    bf16*  xt    = (bf16*)d_out;

    probe_kernel<<<1, 64, 0, stream>>>(x, flag);
    prep_w2t_kernel<<<(C_*C_+255)/256, 256, 0, stream>>>(dcw2, w2t, flag);
    prep_misc_kernel<<<(PM_TOTAL+255)/256, 256, 0, stream>>>(
        dcw, cbw, sa1w, sa2w, sa3w, q_b, k_b, v_b, c_b, query,
        sa1b, sa2b, sa3b, w2, w4, wts, v_w, c_w,
        dwt, cbwf, saw, vecs, vwt, cwt, flag);
    cvt_tr_kernel<<<dim3(B_, C_/TCH), 256, 0, stream>>>(x, xt, flag);

    qproj1_kernel<<<C_, 64, 0, stream>>>(q_w, vecs, qp, flag);
    qproj2_kernel<<<9, 256, 0, stream>>>(k_w, vecs, qp, qk, flag);
    f1_kernel<<<B_, 512, 0, stream>>>(xt, qk, vecs, pooled, mm);
    proj_kernel<<<B_, C_, 0, stream>>>(pooled, mm, vwt, cwt, dcw2, vecs, xq, yq, flag);

    corr2g_kernel<<<dim3(B_, 6), 256, 0, stream>>>(xt, yq, vecs, g);
    corr2z_kernel<<<B_, 512, 0, stream>>>(xt, g, zbuf);
    corr2f_kernel<<<dim3(B_, 4), 128, 0, stream>>>(zbuf, w2t, feat);

    xdown_kernel<<<dim3(B_, 25), 256, 0, stream>>>(xt, dwt, xd);
    dwconv_kernel<<<dim3(N_*RC_, T_), 256, 0, stream>>>(xd, saw, vecs, aggs);
    final_kernel<<<dim3(B_, 4), 256, 0, stream>>>(aggs, cbwf, feat, out);
}

// Round 4
// 682.484 us; speedup vs baseline: 1.1720x; 1.0577x over previous
//
#include <hip/hip_runtime.h>
#include <hip/hip_bf16.h>

using bf16 = __hip_bfloat16;
typedef __attribute__((ext_vector_type(4))) unsigned short ushort4v;

#define N_  2
#define C_  512
#define T_  96
#define H_  14
#define W_  14
#define HW_ 196
#define RC_ 32
#define B_  (N_*T_)    // 192
#define SC_ (T_*HW_)   // 18816 elems per channel (input layout)
#define XTOT (N_*C_*T_*HW_)  // 19267584

// fp32 vec arena offsets
#define VQB   0
#define VKB   512
#define VVB   1024
#define VCB   1536
#define VQRY  2048
#define VSAB  2560   // 96 (3x32)
#define VW2   2688   // 6
#define VW4   2696   // 3
#define VWTS  2700   // 3
#define VECS_TOTAL 2720

__device__ __forceinline__ float b2f(bf16 v){ return __bfloat162float(v); }
__device__ __forceinline__ float u2f(unsigned short u){ return __uint_as_float(((unsigned)u)<<16); }
__device__ __forceinline__ float sigm(float x){ return 1.f/(1.f+__expf(-x)); }
__device__ __forceinline__ unsigned short f2bu(float f){
    bf16 b = __float2bfloat16(f);
    return *(unsigned short*)&b;
}

__device__ __forceinline__ float ldd(const void* p, size_t i, bool f32){
    if (f32) return ((const float*)p)[i];
    else     return b2f(((const bf16*)p)[i]);
}

// ---------- probe: fp32 vs bf16 inputs ----------
__global__ void probe_kernel(const void* __restrict__ x, int* __restrict__ flag){
    if (blockIdx.x==0 && threadIdx.x==0){
        const unsigned short* h = (const unsigned short*)x;
        int wild = 0;
        for (int i=0;i<128;i++){
            int e = (h[i] >> 7) & 0xFF;
            if (e < 100 || e > 150) wild++;
        }
        flag[0] = (wild > 16) ? 1 : 0;   // 1 => fp32 inputs
    }
}

// ---------- prep: down_conv2_w -> fp32 transposed  w2t[e][o] = W[o][e] ----------
__global__ void prep_w2t_kernel(const void* __restrict__ dcw2, float* __restrict__ w2t,
                                const int* __restrict__ flag){
    bool f32 = flag[0]!=0;
    int i = blockIdx.x*256 + threadIdx.x;
    if (i < C_*C_){
        int in = i / C_, out = i % C_;
        w2t[i] = ldd(dcw2, (size_t)out*C_ + in, f32);
    }
}

// ---------- prep: small weights -> fp32 arenas (+ v_w/c_w transposes) ----------
#define PM_OLD (16384+16384+7776+512*5+96+6+3+3)
#define PM_TOTAL (PM_OLD + 262144 + 262144)
__global__ void prep_misc_kernel(const void* dcw, const void* cbw,
                                 const void* sa1w, const void* sa2w, const void* sa3w,
                                 const void* q_b, const void* k_b, const void* v_b,
                                 const void* c_b, const void* query,
                                 const void* sa1b, const void* sa2b, const void* sa3b,
                                 const void* w2, const void* w4, const void* wts,
                                 const void* v_w, const void* c_w,
                                 float* __restrict__ dwt, float* __restrict__ cbwf,
                                 float* __restrict__ saw, float* __restrict__ vecs,
                                 float* __restrict__ vwt, float* __restrict__ cwt,
                                 const int* __restrict__ flag){
    bool f32 = flag[0]!=0;
    int i = blockIdx.x*256 + threadIdx.x;
    if (i >= PM_TOTAL) return;
    if (i < 16384){ int c=i>>5, r=i&31; dwt[i] = ldd(dcw, (size_t)r*C_+c, f32); return; }
    i -= 16384;
    if (i < 16384){ cbwf[i] = ldd(cbw, i, f32); return; }
    i -= 16384;
    if (i < 7776){
        const void* s = (i<2592)? sa1w : ((i<5184)? sa2w : sa3w);
        int j = (i<2592)? i : ((i<5184)? i-2592 : i-5184);
        saw[i] = ldd(s, j, f32); return;
    }
    i -= 7776;
    if (i < 512){ vecs[VQB +i] = ldd(q_b,  i, f32); return; } i -= 512;
    if (i < 512){ vecs[VKB +i] = ldd(k_b,  i, f32); return; } i -= 512;
    if (i < 512){ vecs[VVB +i] = ldd(v_b,  i, f32); return; } i -= 512;
    if (i < 512){ vecs[VCB +i] = ldd(c_b,  i, f32); return; } i -= 512;
    if (i < 512){ vecs[VQRY+i] = ldd(query,i, f32); return; } i -= 512;
    if (i < 96){
        const void* s = (i<32)? sa1b : ((i<64)? sa2b : sa3b);
        vecs[VSAB+i] = ldd(s, i&31, f32); return;
    }
    i -= 96;
    if (i < 6){ vecs[VW2+i] = ldd(w2, i, f32); return; } i -= 6;
    if (i < 3){ vecs[VW4+i] = ldd(w4, i, f32); return; } i -= 3;
    if (i < 3){ vecs[VWTS+i] = ldd(wts, i, f32); return; } i -= 3;
    if (i < 262144){ int r=i/C_, c=i%C_; vwt[i] = ldd(v_w, (size_t)c*C_+r, f32); return; }
    i -= 262144;
    { int r=i/C_, c=i%C_; cwt[i] = ldd(c_w, (size_t)c*C_+r, f32); }
}

// ---------- cvt_tr: x (n,c,t,l) -> xt (n,t,l,c) bf16, LDS-tiled transpose ----------
#define TCH 128
__global__ void __launch_bounds__(256) cvt_tr_kernel(const void* __restrict__ x,
                                                     bf16* __restrict__ xt,
                                                     const int* __restrict__ flag){
    bool f32 = flag[0]!=0;
    int bt = blockIdx.x;               // n*T+t
    int n = bt / T_, t = bt % T_;
    int c0 = blockIdx.y * TCH;
    __shared__ bf16 tile[TCH*197];     // +1 elem pad per row
    int tid = threadIdx.x;
    const size_t ibase = (((size_t)n*C_ + c0)*T_ + t)*HW_;
    for (int i=tid; i<TCH*HW_; i+=256){
        int cr = i / HW_, l = i - cr*HW_;
        tile[cr*197 + l] = __float2bfloat16(ldd(x, ibase + (size_t)cr*SC_ + l, f32));
    }
    __syncthreads();
    bf16* obase = xt + (size_t)bt*HW_*C_ + c0;
    for (int i=tid; i<HW_*TCH; i+=256){
        int l = i >> 7, cl = i & 127;
        obase[(size_t)l*C_ + cl] = tile[cl*197 + l];
    }
}

// ---------- K1a: qp[c] = (query . q_w[c,:] + q_b[c]) * C^-0.5 ----------
__global__ void __launch_bounds__(64) qproj1_kernel(const void* __restrict__ q_w,
        const float* __restrict__ vecs, float* __restrict__ qp,
        const int* __restrict__ flag){
    bool f32 = flag[0]!=0;
    int c = blockIdx.x;
    int lane = threadIdx.x;
    float acc = 0.f;
    #pragma unroll
    for (int i=lane;i<C_;i+=64)
        acc += vecs[VQRY+i] * ldd(q_w, (size_t)c*C_+i, f32);
    #pragma unroll
    for (int off=32; off>0; off>>=1) acc += __shfl_down(acc, off);
    if (lane==0) qp[c] = (acc + vecs[VQB+c]) * 0.044194173824159216f;   // 512^-0.5
}

// ---------- K1b: qk[c] = sum_i qp[i]*k_w[i*C+c];  qk[C] = qp . k_b ----------
__global__ void __launch_bounds__(256) qproj2_kernel(const void* __restrict__ k_w,
        const float* __restrict__ vecs, const float* __restrict__ qp,
        float* __restrict__ qk_out, const int* __restrict__ flag){
    bool f32 = flag[0]!=0;
    __shared__ float sh[256];
    int tid = threadIdx.x;
    if (blockIdx.x < 8){
        int c = blockIdx.x*64 + (tid&63);
        int isub = tid>>6;
        float acc = 0.f;
        for (int i=isub*128; i<isub*128+128; i++)
            acc += qp[i] * ldd(k_w, (size_t)i*C_ + c, f32);
        sh[tid] = acc;
        __syncthreads();
        if (tid < 64)
            qk_out[c] = sh[tid] + sh[tid+64] + sh[tid+128] + sh[tid+192];
    } else {
        float acc = 0.f;
        for (int i=tid;i<C_;i+=256) acc += qp[i]*vecs[VKB+i];
        sh[tid] = acc;
        __syncthreads();
        if (tid==0){
            float d=0.f;
            for (int i=0;i<256;i++) d += sh[i];
            qk_out[C_] = d;
        }
    }
}

// ---------- F1: logits + softmax + pooled/mm, all wave-per-row coalesced ----------
__global__ void __launch_bounds__(512) f1_kernel(const bf16* __restrict__ xt,
        const float* __restrict__ qk, const float* __restrict__ vecs,
        float* __restrict__ pooled, float* __restrict__ mm){
    int b = blockIdx.x;
    __shared__ float sm[HW_];
    __shared__ float red[2];
    __shared__ float r8[8][C_];
    int tid = threadIdx.x, wave = tid>>6, lane = tid&63;
    float qkr[8];
    #pragma unroll
    for (int k=0;k<4;k++){ qkr[k] = qk[lane*4+k]; qkr[4+k] = qk[256+lane*4+k]; }
    float qkC = qk[C_];
    const bf16* fbase = xt + (size_t)b*HW_*C_;
    for (int l=wave; l<HW_; l+=8){
        const bf16* row = fbase + (size_t)l*C_;
        ushort4v u1 = *(const ushort4v*)(row + lane*4);
        ushort4v u2 = *(const ushort4v*)(row + 256 + lane*4);
        float a = 0.f;
        #pragma unroll
        for (int k=0;k<4;k++) a += qkr[k]*u2f(u1[k]) + qkr[4+k]*u2f(u2[k]);
        #pragma unroll
        for (int off=32; off>0; off>>=1) a += __shfl_down(a, off);
        if (lane==0) sm[l] = a + qkC;
    }
    __syncthreads();
    if (tid < 64){
        float m = -1e30f;
        for (int l=tid; l<HW_; l+=64) m = fmaxf(m, sm[l]);
        #pragma unroll
        for (int off=32; off>0; off>>=1) m = fmaxf(m, __shfl_down(m, off));
        if (tid==0) red[0] = m;
    }
    __syncthreads();
    if (tid < HW_) sm[tid] = __expf(sm[tid]-red[0]);
    __syncthreads();
    if (tid < 64){
        float s = 0.f;
        for (int l=tid; l<HW_; l+=64) s += sm[l];
        #pragma unroll
        for (int off=32; off>0; off>>=1) s += __shfl_down(s, off);
        if (tid==0) red[1] = 1.f/s;
    }
    __syncthreads();
    if (tid < HW_) sm[tid] *= red[1];
    __syncthreads();
    // pass 2: per-lane 8-channel accumulators over wave's row subset
    float sa[8], pa[8], ma[8];
    #pragma unroll
    for (int k=0;k<8;k++){ sa[k]=0.f; pa[k]=0.f; ma[k]=-1e30f; }
    for (int l=wave; l<HW_; l+=8){
        const bf16* row = fbase + (size_t)l*C_;
        ushort4v u1 = *(const ushort4v*)(row + lane*4);
        ushort4v u2 = *(const ushort4v*)(row + 256 + lane*4);
        float smv = sm[l];
        #pragma unroll
        for (int k=0;k<4;k++){
            float v1 = u2f(u1[k]), v2 = u2f(u2[k]);
            sa[k]   += v1; ma[k]   = fmaxf(ma[k],  v1); pa[k]   += smv*v1;
            sa[4+k] += v2; ma[4+k] = fmaxf(ma[4+k],v2); pa[4+k] += smv*v2;
        }
    }
    int c1 = lane*4, c2 = 256+lane*4;
    #pragma unroll
    for (int k=0;k<4;k++){ r8[wave][c1+k]=pa[k]; r8[wave][c2+k]=pa[4+k]; }
    __syncthreads();
    int c = tid;
    float pltot = 0.f;
    #pragma unroll
    for (int w=0;w<8;w++) pltot += r8[w][c];
    __syncthreads();
    #pragma unroll
    for (int k=0;k<4;k++){ r8[wave][c1+k]=sa[k]; r8[wave][c2+k]=sa[4+k]; }
    __syncthreads();
    float stot = 0.f;
    #pragma unroll
    for (int w=0;w<8;w++) stot += r8[w][c];
    __syncthreads();
    #pragma unroll
    for (int k=0;k<4;k++){ r8[wave][c1+k]=ma[k]; r8[wave][c2+k]=ma[4+k]; }
    __syncthreads();
    float mtot = -1e30f;
    #pragma unroll
    for (int w=0;w<8;w++) mtot = fmaxf(mtot, r8[w][c]);
    pooled[(size_t)b*C_+c] = pltot;
    float w40=vecs[VW4+0], w41=vecs[VW4+1];
    mm[(size_t)b*C_+c] = stot*(1.f/HW_)*w40 + mtot*w41;
}

// ---------- proj: v-proj -> c-proj -> xq -> yq (all coalesced) ----------
__global__ void __launch_bounds__(512) proj_kernel(const float* __restrict__ pooled,
        const float* __restrict__ mm, const float* __restrict__ vwt,
        const float* __restrict__ cwt, const void* __restrict__ dcw2,
        const float* __restrict__ vecs, float* __restrict__ xq,
        float* __restrict__ yq, const int* __restrict__ flag){
    bool f32 = flag[0]!=0;
    int b = blockIdx.x, c = threadIdx.x;       // 512 threads
    __shared__ float p_s[C_];
    __shared__ float pre_s[C_];
    __shared__ float xq_s[C_];
    p_s[c] = pooled[(size_t)b*C_ + c];
    __syncthreads();
    float pre = vecs[VVB+c];
    for (int i=0;i<C_;i++) pre += p_s[i]*vwt[(size_t)i*C_+c];
    pre_s[c] = pre;
    __syncthreads();
    float att = vecs[VCB+c];
    for (int i=0;i<C_;i++) att += pre_s[i]*cwt[(size_t)i*C_+c];
    float xqv = mm[(size_t)b*C_+c] + vecs[VW4+2]*att;
    xq[(size_t)b*C_+c] = xqv;
    xq_s[c] = xqv;
    __syncthreads();
    float yqv = 0.f;
    for (int i=0;i<C_;i++) yqv += xq_s[i]*ldd(dcw2, (size_t)i*C_+c, f32);
    yq[(size_t)b*C_+c] = yqv;
}

// ---------- corr2gz: fused gates + z-partials, frame-quarter blocks ----------
// grid (192 frames, 4 quarters) x 512 thr. Each frame-quarter staged to LDS ONCE;
// gates for the 6 target b's computed wave-per-row; z-partials thread-per-e.
#define QROWS 49
#define B6C   (B_*6*C_)   // 589824
__global__ void __launch_bounds__(512) corr2gz_kernel(const bf16* __restrict__ xt,
        const float* __restrict__ yq, const float* __restrict__ vecs,
        float* __restrict__ zpart){
    const int offs[6] = {-3,-2,-1,1,2,3};
    int frame = blockIdx.x;            // n*T_ + t'
    int qq = blockIdx.y;               // row quarter
    int n = frame / T_, tp = frame % T_;
    int l0 = qq*QROWS;
    __shared__ bf16 xs[QROWS*C_];      // 50176 B
    __shared__ float a_s[6][QROWS];
    int tid = threadIdx.x, lane = tid&63, wave = tid>>6;
    // stage 49 rows, coalesced ushort4
    const ushort4v* src = (const ushort4v*)(xt + ((size_t)frame*HW_ + l0)*C_);
    ushort4v* dst = (ushort4v*)xs;
    for (int i=tid; i<QROWS*C_/4; i+=512) dst[i] = src[i];
    // target validity + yq registers + weights
    bool val[6]; float w2r[6]; float yqr[6][8];
    #pragma unroll
    for (int jj=0;jj<6;jj++){
        int tt = tp - offs[jj];
        val[jj] = (tt>=0 && tt<T_);
        w2r[jj] = vecs[VW2+jj];
        if (val[jj]){
            const float* yb = yq + (size_t)(n*T_+tt)*C_;
            #pragma unroll
            for (int k=0;k<4;k++){ yqr[jj][k]=yb[lane*4+k]; yqr[jj][4+k]=yb[256+lane*4+k]; }
        } else {
            #pragma unroll
            for (int k=0;k<8;k++) yqr[jj][k]=0.f;
        }
    }
    __syncthreads();
    // gates: wave-per-row, 6 targets at once
    for (int li=wave; li<QROWS; li+=8){
        ushort4v u1 = *(const ushort4v*)(xs + li*C_ + lane*4);
        ushort4v u2 = *(const ushort4v*)(xs + li*C_ + 256 + lane*4);
        float xf[8];
        #pragma unroll
        for (int k=0;k<4;k++){ xf[k]=u2f(u1[k]); xf[4+k]=u2f(u2[k]); }
        float a[6];
        #pragma unroll
        for (int jj=0;jj<6;jj++){
            float s=0.f;
            #pragma unroll
            for (int k=0;k<8;k++) s += yqr[jj][k]*xf[k];
            a[jj]=s;
        }
        #pragma unroll
        for (int off=32; off>0; off>>=1){
            #pragma unroll
            for (int jj=0;jj<6;jj++) a[jj] += __shfl_down(a[jj], off);
        }
        if (lane==0){
            #pragma unroll
            for (int jj=0;jj<6;jj++)
                a_s[jj][li] = val[jj] ? w2r[jj]*(sigm(w2r[jj]*a[jj])-0.5f) : 0.f;
        }
    }
    __syncthreads();
    // z-partials: thread-per-e over the 49 staged rows
    int e = tid;
    float acc[6] = {0.f,0.f,0.f,0.f,0.f,0.f};
    for (int li=0; li<QROWS; ++li){
        float xv = b2f(xs[li*C_ + e]);
        #pragma unroll
        for (int jj=0;jj<6;jj++) acc[jj] += a_s[jj][li]*xv;
    }
    #pragma unroll
    for (int jj=0;jj<6;jj++){
        if (val[jj]){
            int b = n*T_ + (tp - offs[jj]);
            zpart[(size_t)qq*B6C + ((size_t)b*6+jj)*C_ + e] = acc[jj];
        }
    }
}

// ---------- corr2f: z = sum(valid zparts); feat[b][c] = sum_e w2t[e][c]*z[e] ----------
__global__ void __launch_bounds__(128) corr2f_kernel(const float* __restrict__ zpart,
        const float* __restrict__ w2t, float* __restrict__ feat){
    const int offs[6] = {-3,-2,-1,1,2,3};
    int b = blockIdx.x, c0 = blockIdx.y*128;
    int t = b % T_;
    int tid = threadIdx.x;
    __shared__ float z_s[C_];
    for (int e=tid; e<C_; e+=128){
        float s = 0.f;
        #pragma unroll
        for (int jj=0;jj<6;jj++){
            int tj = t + offs[jj];
            if (tj<0 || tj>=T_) continue;
            const float* zp = zpart + ((size_t)b*6+jj)*C_ + e;
            s += zp[0] + zp[B6C] + zp[2*B6C] + zp[3*(size_t)B6C];
        }
        z_s[e] = s;
    }
    __syncthreads();
    int c = c0 + tid;
    float acc = 0.f;
    for (int e=0;e<C_;e++) acc += w2t[(size_t)e*C_+c]*z_s[e];
    feat[(size_t)b*C_+c] = acc;
}

// ---------- xdown: x_down = down_conv_w @ x, LDS row-stage (xt layout) ----------
__global__ void __launch_bounds__(256) xdown_kernel(const bf16* __restrict__ xt,
                                                    const float* __restrict__ dwt,
                                                    bf16* __restrict__ xd){
    int b = blockIdx.x, n=b/T_, t=b%T_;
    int l0 = blockIdx.y*8;
    int nl = HW_ - l0; if (nl > 8) nl = 8;
    __shared__ bf16 xs[8*C_];
    int tid = threadIdx.x;
    const bf16* fbase = xt + (size_t)b*HW_*C_ + (size_t)l0*C_;
    for (int i=tid; i<nl*C_; i+=256) xs[i] = fbase[i];
    __syncthreads();
    int r = tid>>3, ls = tid&7;
    if (ls < nl){
        float acc = 0.f;
        for (int c=0;c<C_;c++)
            acc += dwt[c*RC_ + r] * b2f(xs[ls*C_ + c]);
        xd[(((size_t)n*RC_+r)*T_ + t)*HW_ + l0 + ls] = __float2bfloat16(acc);
    }
}

// ---------- dwconv: padded-tile version, one (n,r,t) per block ----------
#define TPAD 21
#define TROW 20
#define TFRM (TROW*TPAD)   // 420
__global__ void __launch_bounds__(256) dwconv_kernel(const bf16* __restrict__ xd,
        const float* __restrict__ saw, const float* __restrict__ vecs,
        float* __restrict__ aggs){
    int nr = blockIdx.x;            // n*RC_+r
    int t  = blockIdx.y;
    int r  = nr % RC_;
    __shared__ float tile[9*TFRM];
    __shared__ float wsm[3][81];
    int tid = threadIdx.x;          // 256
    for (int i=tid;i<9*TFRM;i+=256) tile[i] = 0.f;
    if (tid < 81){
        wsm[0][tid]=saw[       r*81+tid];
        wsm[1][tid]=saw[2592 + r*81+tid];
        wsm[2][tid]=saw[5184 + r*81+tid];
    }
    __syncthreads();
    const bf16* base = xd + (size_t)nr*T_*HW_;
    for (int i=tid;i<9*HW_;i+=256){
        int kt = i/HW_, hw = i - kt*HW_;
        int tg = t - 4 + kt;
        if (tg>=0 && tg<T_){
            int h = hw/W_, w = hw - h*W_;
            tile[kt*TFRM + (h+3)*TPAD + (w+3)] = b2f(base[(size_t)tg*HW_ + hw]);
        }
    }
    __syncthreads();
    if (tid < HW_){
        int h = tid/W_, w = tid - h*W_;
        float w0=vecs[VWTS+0], w1=vecs[VWTS+1], w2v=vecs[VWTS+2];
        float cbias = w0*vecs[VSAB+r] + w1*vecs[VSAB+32+r] + w2v*vecs[VSAB+64+r];
        float bacc[3];
        #pragma unroll
        for (int br=0;br<3;br++){
            int d = br+1;
            float s = 0.f;
            #pragma unroll
            for (int kt=0;kt<9;kt++){
                const float* tb = &tile[kt*TFRM + (h+3-d)*TPAD + (w+3-d)];
                const float* wp = &wsm[br][kt*9];
                s += wp[0]*tb[0]          + wp[1]*tb[d]          + wp[2]*tb[2*d]
                   + wp[3]*tb[d*TPAD]     + wp[4]*tb[d*TPAD+d]   + wp[5]*tb[d*TPAD+2*d]
                   + wp[6]*tb[2*d*TPAD]   + wp[7]*tb[2*d*TPAD+d] + wp[8]*tb[2*d*TPAD+2*d];
            }
            bacc[br] = s;
        }
        float acc = cbias + w0*bacc[0] + w1*bacc[1] + w2v*bacc[2];
        aggs[(size_t)nr*T_*HW_ + (size_t)t*HW_ + tid] = acc;
    }
}

// ---------- final: conv_back (reg-resident agg) + gate * feat -> fp32 out ----------
__global__ void __launch_bounds__(256) final_kernel(const float* __restrict__ aggs,
                                                    const float* __restrict__ cbwf,
                                                    const float* __restrict__ feat,
                                                    float* __restrict__ out){
    int b = blockIdx.x, n = b/T_, t = b%T_;
    int c0 = blockIdx.y*128;
    int hw = threadIdx.x;
    if (hw >= HW_) return;
    float ra[RC_];
    #pragma unroll
    for (int r=0;r<RC_;r++)
        ra[r] = aggs[(((size_t)n*RC_+r)*T_ + t)*HW_ + hw];
    const float* fb = feat + (size_t)b*C_;
    for (int ci=0;ci<128;ci++){
        int c = c0+ci;
        const float* wr = cbwf + c*RC_;    // wave-uniform
        float a = 0.f;
        #pragma unroll
        for (int r=0;r<RC_;r++) a += wr[r]*ra[r];
        out[(((size_t)n*C_+c)*T_ + t)*HW_ + hw] = fb[c]*(sigm(a)-0.5f);
    }
}

extern "C" void kernel_launch(void* const* d_in, const int* in_sizes, int n_in,
                              void* d_out, int out_size, void* d_ws, size_t ws_size,
                              hipStream_t stream){
    const void* x      = d_in[0];
    const void* dcw2   = d_in[1];
    const void* dcw    = d_in[2];
    const void* cbw    = d_in[3];
    const void* w2     = d_in[4];
    const void* w4     = d_in[5];
    const void* wts    = d_in[6];
    const void* query  = d_in[7];
    const void* q_w    = d_in[8];
    const void* q_b    = d_in[9];
    const void* k_w    = d_in[10];
    const void* k_b    = d_in[11];
    const void* v_w    = d_in[12];
    const void* v_b    = d_in[13];
    const void* c_w    = d_in[14];
    const void* c_b    = d_in[15];
    const void* sa1w   = d_in[16];
    const void* sa1b   = d_in[17];
    const void* sa2w   = d_in[18];
    const void* sa2b   = d_in[19];
    const void* sa3w   = d_in[20];
    const void* sa3b   = d_in[21];
    float* out = (float*)d_out;

    // workspace layout — ~12.5 MB
    float* ws    = (float*)d_ws;
    int*   flag  = (int*)ws;               // 16
    float* qk    = ws + 16;                // 1024
    float* qp    = qk + 1024;              // 1024 (uses 512)
    float* pooled= qp + 1024;              // 98304
    float* mm    = pooled + 98304;         // 98304
    float* xq    = mm + 98304;             // 98304
    float* yq    = xq + 98304;             // 98304
    float* feat  = yq + 98304;             // 98304
    float* w2t   = feat + 98304;           // 262144
    float* vwt   = w2t + 262144;           // 262144
    float* cwt   = vwt + 262144;           // 262144
    float* dwt   = cwt + 262144;           // 16384
    float* cbwf  = dwt + 16384;            // 16384
    float* saw   = cbwf + 16384;           // 7936 (uses 7776)
    float* vecs  = saw + 7936;             // 2720
    float* aggs  = vecs + VECS_TOTAL;      // 1204224 fp32
    bf16*  xd    = (bf16*)(aggs + 1204224);// 1204224 bf16
    // xt (channel-last bf16 x) in first 38.5 MB of d_out; zpart (4x2.36 MB)
    // in the next 9.4 MB. Both fully consumed before final_kernel writes d_out.
    bf16*  xt    = (bf16*)d_out;
    float* zpart = (float*)(xt + (size_t)XTOT);

    probe_kernel<<<1, 64, 0, stream>>>(x, flag);
    prep_w2t_kernel<<<(C_*C_+255)/256, 256, 0, stream>>>(dcw2, w2t, flag);
    prep_misc_kernel<<<(PM_TOTAL+255)/256, 256, 0, stream>>>(
        dcw, cbw, sa1w, sa2w, sa3w, q_b, k_b, v_b, c_b, query,
        sa1b, sa2b, sa3b, w2, w4, wts, v_w, c_w,
        dwt, cbwf, saw, vecs, vwt, cwt, flag);
    cvt_tr_kernel<<<dim3(B_, C_/TCH), 256, 0, stream>>>(x, xt, flag);

    qproj1_kernel<<<C_, 64, 0, stream>>>(q_w, vecs, qp, flag);
    qproj2_kernel<<<9, 256, 0, stream>>>(k_w, vecs, qp, qk, flag);
    f1_kernel<<<B_, 512, 0, stream>>>(xt, qk, vecs, pooled, mm);
    proj_kernel<<<B_, C_, 0, stream>>>(pooled, mm, vwt, cwt, dcw2, vecs, xq, yq, flag);

    corr2gz_kernel<<<dim3(B_, 4), 512, 0, stream>>>(xt, yq, vecs, zpart);
    corr2f_kernel<<<dim3(B_, 4), 128, 0, stream>>>(zpart, w2t, feat);

    xdown_kernel<<<dim3(B_, 25), 256, 0, stream>>>(xt, dwt, xd);
    dwconv_kernel<<<dim3(N_*RC_, T_), 256, 0, stream>>>(xd, saw, vecs, aggs);
    final_kernel<<<dim3(B_, 4), 256, 0, stream>>>(aggs, cbwf, feat, out);
}

// Round 5
// 678.302 us; speedup vs baseline: 1.1792x; 1.0062x over previous
//
#include <hip/hip_runtime.h>
#include <hip/hip_bf16.h>

using bf16 = __hip_bfloat16;
typedef __attribute__((ext_vector_type(4))) unsigned short ushort4v;

#define N_  2
#define C_  512
#define T_  96
#define H_  14
#define W_  14
#define HW_ 196
#define RC_ 32
#define B_  (N_*T_)    // 192
#define SC_ (T_*HW_)   // 18816 elems per channel (input layout)
#define XTOT (N_*C_*T_*HW_)  // 19267584

// fp32 vec arena offsets
#define VQB   0
#define VKB   512
#define VVB   1024
#define VCB   1536
#define VQRY  2048
#define VSAB  2560   // 96 (3x32)
#define VW2   2688   // 6
#define VW4   2696   // 3
#define VWTS  2700   // 3
#define VECS_TOTAL 2720

__device__ __forceinline__ float b2f(bf16 v){ return __bfloat162float(v); }
__device__ __forceinline__ float u2f(unsigned short u){ return __uint_as_float(((unsigned)u)<<16); }
__device__ __forceinline__ float sigm(float x){ return 1.f/(1.f+__expf(-x)); }
__device__ __forceinline__ unsigned short f2bu(float f){
    bf16 b = __float2bfloat16(f);
    return *(unsigned short*)&b;
}

__device__ __forceinline__ float ldd(const void* p, size_t i, bool f32){
    if (f32) return ((const float*)p)[i];
    else     return b2f(((const bf16*)p)[i]);
}

// ---------- probe: fp32 vs bf16 inputs ----------
__global__ void probe_kernel(const void* __restrict__ x, int* __restrict__ flag){
    if (blockIdx.x==0 && threadIdx.x==0){
        const unsigned short* h = (const unsigned short*)x;
        int wild = 0;
        for (int i=0;i<128;i++){
            int e = (h[i] >> 7) & 0xFF;
            if (e < 100 || e > 150) wild++;
        }
        flag[0] = (wild > 16) ? 1 : 0;   // 1 => fp32 inputs
    }
}

// ---------- prep: down_conv2_w -> fp32 transposed  w2t[e][o] = W[o][e] ----------
__global__ void prep_w2t_kernel(const void* __restrict__ dcw2, float* __restrict__ w2t,
                                const int* __restrict__ flag){
    bool f32 = flag[0]!=0;
    int i = blockIdx.x*256 + threadIdx.x;
    if (i < C_*C_){
        int in = i / C_, out = i % C_;
        w2t[i] = ldd(dcw2, (size_t)out*C_ + in, f32);
    }
}

// ---------- prep: small weights -> fp32 arenas (+ v_w/c_w transposes) ----------
#define PM_OLD (16384+16384+7776+512*5+96+6+3+3)
#define PM_TOTAL (PM_OLD + 262144 + 262144)
__global__ void prep_misc_kernel(const void* dcw, const void* cbw,
                                 const void* sa1w, const void* sa2w, const void* sa3w,
                                 const void* q_b, const void* k_b, const void* v_b,
                                 const void* c_b, const void* query,
                                 const void* sa1b, const void* sa2b, const void* sa3b,
                                 const void* w2, const void* w4, const void* wts,
                                 const void* v_w, const void* c_w,
                                 float* __restrict__ dwt, float* __restrict__ cbwf,
                                 float* __restrict__ saw, float* __restrict__ vecs,
                                 float* __restrict__ vwt, float* __restrict__ cwt,
                                 const int* __restrict__ flag){
    bool f32 = flag[0]!=0;
    int i = blockIdx.x*256 + threadIdx.x;
    if (i >= PM_TOTAL) return;
    if (i < 16384){ int c=i>>5, r=i&31; dwt[i] = ldd(dcw, (size_t)r*C_+c, f32); return; }
    i -= 16384;
    if (i < 16384){ cbwf[i] = ldd(cbw, i, f32); return; }
    i -= 16384;
    if (i < 7776){
        const void* s = (i<2592)? sa1w : ((i<5184)? sa2w : sa3w);
        int j = (i<2592)? i : ((i<5184)? i-2592 : i-5184);
        saw[i] = ldd(s, j, f32); return;
    }
    i -= 7776;
    if (i < 512){ vecs[VQB +i] = ldd(q_b,  i, f32); return; } i -= 512;
    if (i < 512){ vecs[VKB +i] = ldd(k_b,  i, f32); return; } i -= 512;
    if (i < 512){ vecs[VVB +i] = ldd(v_b,  i, f32); return; } i -= 512;
    if (i < 512){ vecs[VCB +i] = ldd(c_b,  i, f32); return; } i -= 512;
    if (i < 512){ vecs[VQRY+i] = ldd(query,i, f32); return; } i -= 512;
    if (i < 96){
        const void* s = (i<32)? sa1b : ((i<64)? sa2b : sa3b);
        vecs[VSAB+i] = ldd(s, i&31, f32); return;
    }
    i -= 96;
    if (i < 6){ vecs[VW2+i] = ldd(w2, i, f32); return; } i -= 6;
    if (i < 3){ vecs[VW4+i] = ldd(w4, i, f32); return; } i -= 3;
    if (i < 3){ vecs[VWTS+i] = ldd(wts, i, f32); return; } i -= 3;
    if (i < 262144){ int r=i/C_, c=i%C_; vwt[i] = ldd(v_w, (size_t)c*C_+r, f32); return; }
    i -= 262144;
    { int r=i/C_, c=i%C_; cwt[i] = ldd(c_w, (size_t)c*C_+r, f32); }
}

// ---------- cvt_tr: x (n,c,t,l) -> xt (n,t,l,c) bf16, LDS-tiled transpose ----------
#define TCH 128
__global__ void __launch_bounds__(256) cvt_tr_kernel(const void* __restrict__ x,
                                                     bf16* __restrict__ xt,
                                                     const int* __restrict__ flag){
    bool f32 = flag[0]!=0;
    int bt = blockIdx.x;               // n*T+t
    int n = bt / T_, t = bt % T_;
    int c0 = blockIdx.y * TCH;
    __shared__ bf16 tile[TCH*197];     // +1 elem pad per row
    int tid = threadIdx.x;
    const size_t ibase = (((size_t)n*C_ + c0)*T_ + t)*HW_;
    for (int i=tid; i<TCH*HW_; i+=256){
        int cr = i / HW_, l = i - cr*HW_;
        tile[cr*197 + l] = __float2bfloat16(ldd(x, ibase + (size_t)cr*SC_ + l, f32));
    }
    __syncthreads();
    bf16* obase = xt + (size_t)bt*HW_*C_ + c0;
    for (int i=tid; i<HW_*TCH/4; i+=256){
        int l = i >> 5, cg = (i & 31)*4;
        ushort4v u;
        #pragma unroll
        for (int k=0;k<4;k++) u[k] = *(unsigned short*)&tile[(cg+k)*197 + l];
        *(ushort4v*)(obase + (size_t)l*C_ + cg) = u;
    }
}

// ---------- K1a: qp[c] = (query . q_w[c,:] + q_b[c]) * C^-0.5 ----------
__global__ void __launch_bounds__(64) qproj1_kernel(const void* __restrict__ q_w,
        const float* __restrict__ vecs, float* __restrict__ qp,
        const int* __restrict__ flag){
    bool f32 = flag[0]!=0;
    int c = blockIdx.x;
    int lane = threadIdx.x;
    float acc = 0.f;
    #pragma unroll
    for (int i=lane;i<C_;i+=64)
        acc += vecs[VQRY+i] * ldd(q_w, (size_t)c*C_+i, f32);
    #pragma unroll
    for (int off=32; off>0; off>>=1) acc += __shfl_down(acc, off);
    if (lane==0) qp[c] = (acc + vecs[VQB+c]) * 0.044194173824159216f;   // 512^-0.5
}

// ---------- K1b: qk[c] = sum_i qp[i]*k_w[i*C+c];  qk[C] = qp . k_b ----------
__global__ void __launch_bounds__(256) qproj2_kernel(const void* __restrict__ k_w,
        const float* __restrict__ vecs, const float* __restrict__ qp,
        float* __restrict__ qk_out, const int* __restrict__ flag){
    bool f32 = flag[0]!=0;
    __shared__ float sh[256];
    int tid = threadIdx.x;
    if (blockIdx.x < 8){
        int c = blockIdx.x*64 + (tid&63);
        int isub = tid>>6;
        float acc = 0.f;
        for (int i=isub*128; i<isub*128+128; i++)
            acc += qp[i] * ldd(k_w, (size_t)i*C_ + c, f32);
        sh[tid] = acc;
        __syncthreads();
        if (tid < 64)
            qk_out[c] = sh[tid] + sh[tid+64] + sh[tid+128] + sh[tid+192];
    } else {
        float acc = 0.f;
        for (int i=tid;i<C_;i+=256) acc += qp[i]*vecs[VKB+i];
        sh[tid] = acc;
        __syncthreads();
        if (tid==0){
            float d=0.f;
            for (int i=0;i<256;i++) d += sh[i];
            qk_out[C_] = d;
        }
    }
}

// ---------- F1: logits + softmax + pooled/mm, all wave-per-row coalesced ----------
__global__ void __launch_bounds__(512) f1_kernel(const bf16* __restrict__ xt,
        const float* __restrict__ qk, const float* __restrict__ vecs,
        float* __restrict__ pooled, float* __restrict__ mm){
    int b = blockIdx.x;
    __shared__ float sm[HW_];
    __shared__ float red[2];
    __shared__ float r8[8][C_];
    int tid = threadIdx.x, wave = tid>>6, lane = tid&63;
    float qkr[8];
    #pragma unroll
    for (int k=0;k<4;k++){ qkr[k] = qk[lane*4+k]; qkr[4+k] = qk[256+lane*4+k]; }
    float qkC = qk[C_];
    const bf16* fbase = xt + (size_t)b*HW_*C_;
    for (int l=wave; l<HW_; l+=8){
        const bf16* row = fbase + (size_t)l*C_;
        ushort4v u1 = *(const ushort4v*)(row + lane*4);
        ushort4v u2 = *(const ushort4v*)(row + 256 + lane*4);
        float a = 0.f;
        #pragma unroll
        for (int k=0;k<4;k++) a += qkr[k]*u2f(u1[k]) + qkr[4+k]*u2f(u2[k]);
        #pragma unroll
        for (int off=32; off>0; off>>=1) a += __shfl_down(a, off);
        if (lane==0) sm[l] = a + qkC;
    }
    __syncthreads();
    if (tid < 64){
        float m = -1e30f;
        for (int l=tid; l<HW_; l+=64) m = fmaxf(m, sm[l]);
        #pragma unroll
        for (int off=32; off>0; off>>=1) m = fmaxf(m, __shfl_down(m, off));
        if (tid==0) red[0] = m;
    }
    __syncthreads();
    if (tid < HW_) sm[tid] = __expf(sm[tid]-red[0]);
    __syncthreads();
    if (tid < 64){
        float s = 0.f;
        for (int l=tid; l<HW_; l+=64) s += sm[l];
        #pragma unroll
        for (int off=32; off>0; off>>=1) s += __shfl_down(s, off);
        if (tid==0) red[1] = 1.f/s;
    }
    __syncthreads();
    if (tid < HW_) sm[tid] *= red[1];
    __syncthreads();
    // pass 2: per-lane 8-channel accumulators over wave's row subset
    float sa[8], pa[8], ma[8];
    #pragma unroll
    for (int k=0;k<8;k++){ sa[k]=0.f; pa[k]=0.f; ma[k]=-1e30f; }
    for (int l=wave; l<HW_; l+=8){
        const bf16* row = fbase + (size_t)l*C_;
        ushort4v u1 = *(const ushort4v*)(row + lane*4);
        ushort4v u2 = *(const ushort4v*)(row + 256 + lane*4);
        float smv = sm[l];
        #pragma unroll
        for (int k=0;k<4;k++){
            float v1 = u2f(u1[k]), v2 = u2f(u2[k]);
            sa[k]   += v1; ma[k]   = fmaxf(ma[k],  v1); pa[k]   += smv*v1;
            sa[4+k] += v2; ma[4+k] = fmaxf(ma[4+k],v2); pa[4+k] += smv*v2;
        }
    }
    int c1 = lane*4, c2 = 256+lane*4;
    #pragma unroll
    for (int k=0;k<4;k++){ r8[wave][c1+k]=pa[k]; r8[wave][c2+k]=pa[4+k]; }
    __syncthreads();
    int c = tid;
    float pltot = 0.f;
    #pragma unroll
    for (int w=0;w<8;w++) pltot += r8[w][c];
    __syncthreads();
    #pragma unroll
    for (int k=0;k<4;k++){ r8[wave][c1+k]=sa[k]; r8[wave][c2+k]=sa[4+k]; }
    __syncthreads();
    float stot = 0.f;
    #pragma unroll
    for (int w=0;w<8;w++) stot += r8[w][c];
    __syncthreads();
    #pragma unroll
    for (int k=0;k<4;k++){ r8[wave][c1+k]=ma[k]; r8[wave][c2+k]=ma[4+k]; }
    __syncthreads();
    float mtot = -1e30f;
    #pragma unroll
    for (int w=0;w<8;w++) mtot = fmaxf(mtot, r8[w][c]);
    pooled[(size_t)b*C_+c] = pltot;
    float w40=vecs[VW4+0], w41=vecs[VW4+1];
    mm[(size_t)b*C_+c] = stot*(1.f/HW_)*w40 + mtot*w41;
}

// ---------- proj: v-proj -> c-proj -> xq -> yq (all coalesced) ----------
__global__ void __launch_bounds__(512) proj_kernel(const float* __restrict__ pooled,
        const float* __restrict__ mm, const float* __restrict__ vwt,
        const float* __restrict__ cwt, const void* __restrict__ dcw2,
        const float* __restrict__ vecs, float* __restrict__ xq,
        float* __restrict__ yq, const int* __restrict__ flag){
    bool f32 = flag[0]!=0;
    int b = blockIdx.x, c = threadIdx.x;       // 512 threads
    __shared__ float p_s[C_];
    __shared__ float pre_s[C_];
    __shared__ float xq_s[C_];
    p_s[c] = pooled[(size_t)b*C_ + c];
    __syncthreads();
    float pre = vecs[VVB+c];
    for (int i=0;i<C_;i++) pre += p_s[i]*vwt[(size_t)i*C_+c];
    pre_s[c] = pre;
    __syncthreads();
    float att = vecs[VCB+c];
    for (int i=0;i<C_;i++) att += pre_s[i]*cwt[(size_t)i*C_+c];
    float xqv = mm[(size_t)b*C_+c] + vecs[VW4+2]*att;
    xq[(size_t)b*C_+c] = xqv;
    xq_s[c] = xqv;
    __syncthreads();
    float yqv = 0.f;
    for (int i=0;i<C_;i++) yqv += xq_s[i]*ldd(dcw2, (size_t)i*C_+c, f32);
    yq[(size_t)b*C_+c] = yqv;
}

// ---------- corr2gz: fused gates + z-partials, frame-quarter blocks ----------
// grid (192 frames, 4 quarters) x 512 thr. Each frame-quarter staged to LDS ONCE;
// gates for the 6 target b's computed wave-per-row; z-partials thread-per-e.
#define QROWS 49
#define B6C   (B_*6*C_)   // 589824
__global__ void __launch_bounds__(512) corr2gz_kernel(const bf16* __restrict__ xt,
        const float* __restrict__ yq, const float* __restrict__ vecs,
        float* __restrict__ zpart){
    const int offs[6] = {-3,-2,-1,1,2,3};
    int frame = blockIdx.x;            // n*T_ + t'
    int qq = blockIdx.y;               // row quarter
    int n = frame / T_, tp = frame % T_;
    int l0 = qq*QROWS;
    __shared__ bf16 xs[QROWS*C_];      // 50176 B
    __shared__ float a_s[6][QROWS];
    int tid = threadIdx.x, lane = tid&63, wave = tid>>6;
    // stage 49 rows, coalesced ushort4
    const ushort4v* src = (const ushort4v*)(xt + ((size_t)frame*HW_ + l0)*C_);
    ushort4v* dst = (ushort4v*)xs;
    for (int i=tid; i<QROWS*C_/4; i+=512) dst[i] = src[i];
    // target validity + yq registers + weights
    bool val[6]; float w2r[6]; float yqr[6][8];
    #pragma unroll
    for (int jj=0;jj<6;jj++){
        int tt = tp - offs[jj];
        val[jj] = (tt>=0 && tt<T_);
        w2r[jj] = vecs[VW2+jj];
        if (val[jj]){
            const float* yb = yq + (size_t)(n*T_+tt)*C_;
            #pragma unroll
            for (int k=0;k<4;k++){ yqr[jj][k]=yb[lane*4+k]; yqr[jj][4+k]=yb[256+lane*4+k]; }
        } else {
            #pragma unroll
            for (int k=0;k<8;k++) yqr[jj][k]=0.f;
        }
    }
    __syncthreads();
    // gates: wave-per-row, 6 targets at once
    for (int li=wave; li<QROWS; li+=8){
        ushort4v u1 = *(const ushort4v*)(xs + li*C_ + lane*4);
        ushort4v u2 = *(const ushort4v*)(xs + li*C_ + 256 + lane*4);
        float xf[8];
        #pragma unroll
        for (int k=0;k<4;k++){ xf[k]=u2f(u1[k]); xf[4+k]=u2f(u2[k]); }
        float a[6];
        #pragma unroll
        for (int jj=0;jj<6;jj++){
            float s=0.f;
            #pragma unroll
            for (int k=0;k<8;k++) s += yqr[jj][k]*xf[k];
            a[jj]=s;
        }
        #pragma unroll
        for (int off=32; off>0; off>>=1){
            #pragma unroll
            for (int jj=0;jj<6;jj++) a[jj] += __shfl_down(a[jj], off);
        }
        if (lane==0){
            #pragma unroll
            for (int jj=0;jj<6;jj++)
                a_s[jj][li] = val[jj] ? w2r[jj]*(sigm(w2r[jj]*a[jj])-0.5f) : 0.f;
        }
    }
    __syncthreads();
    // z-partials: thread-per-e over the 49 staged rows
    int e = tid;
    float acc[6] = {0.f,0.f,0.f,0.f,0.f,0.f};
    for (int li=0; li<QROWS; ++li){
        float xv = b2f(xs[li*C_ + e]);
        #pragma unroll
        for (int jj=0;jj<6;jj++) acc[jj] += a_s[jj][li]*xv;
    }
    #pragma unroll
    for (int jj=0;jj<6;jj++){
        if (val[jj]){
            int b = n*T_ + (tp - offs[jj]);
            zpart[(size_t)qq*B6C + ((size_t)b*6+jj)*C_ + e] = acc[jj];
        }
    }
}

// ---------- corr2f: z = sum(valid zparts); feat[b][c] = sum_e w2t[e][c]*z[e] ----------
__global__ void __launch_bounds__(128) corr2f_kernel(const float* __restrict__ zpart,
        const float* __restrict__ w2t, float* __restrict__ feat){
    const int offs[6] = {-3,-2,-1,1,2,3};
    int b = blockIdx.x, c0 = blockIdx.y*128;
    int t = b % T_;
    int tid = threadIdx.x;
    __shared__ float z_s[C_];
    for (int e=tid; e<C_; e+=128){
        float s = 0.f;
        #pragma unroll
        for (int jj=0;jj<6;jj++){
            int tj = t + offs[jj];
            if (tj<0 || tj>=T_) continue;
            const float* zp = zpart + ((size_t)b*6+jj)*C_ + e;
            s += zp[0] + zp[B6C] + zp[2*B6C] + zp[3*(size_t)B6C];
        }
        z_s[e] = s;
    }
    __syncthreads();
    int c = c0 + tid;
    float acc = 0.f;
    for (int e=0;e<C_;e++) acc += w2t[(size_t)e*C_+c]*z_s[e];
    feat[(size_t)b*C_+c] = acc;
}

// ---------- xdown: x_down = down_conv_w @ x, padded-LDS row-stage (xt layout) ----------
// Pad row stride to 520 elems (1040 B): for fixed c, the 8 distinct ls addresses
// land on banks {0,4,...,28} (vs all-same-bank at 1024 B) -> conflict-free.
#define XPAD 8
#define XROW (C_+XPAD)   // 520
__global__ void __launch_bounds__(256) xdown_kernel(const bf16* __restrict__ xt,
                                                    const float* __restrict__ dwt,
                                                    bf16* __restrict__ xd){
    int b = blockIdx.x, n=b/T_, t=b%T_;
    int l0 = blockIdx.y*8;
    int nl = HW_ - l0; if (nl > 8) nl = 8;
    __shared__ bf16 xs[8*XROW];
    int tid = threadIdx.x;
    const bf16* fbase = xt + (size_t)b*HW_*C_ + (size_t)l0*C_;
    for (int i=tid; i<nl*(C_/4); i+=256){
        int row = i >> 7, gc = (i & 127)*4;
        *(ushort4v*)(xs + row*XROW + gc) = *(const ushort4v*)(fbase + (size_t)row*C_ + gc);
    }
    __syncthreads();
    int r = tid>>3, ls = tid&7;
    if (ls < nl){
        float acc = 0.f;
        const bf16* xr = xs + ls*XROW;
        const float* wb = dwt + r;
        for (int c4=0; c4<C_; c4+=4){
            ushort4v u = *(const ushort4v*)(xr + c4);
            const float* wr = wb + c4*RC_;
            acc += wr[0]*u2f(u[0]) + wr[RC_]*u2f(u[1])
                 + wr[2*RC_]*u2f(u[2]) + wr[3*RC_]*u2f(u[3]);
        }
        xd[(((size_t)n*RC_+r)*T_ + t)*HW_ + l0 + ls] = __float2bfloat16(acc);
    }
}

// ---------- dwconv: padded-tile version, one (n,r,t) per block ----------
#define TPAD 21
#define TROW 20
#define TFRM (TROW*TPAD)   // 420
__global__ void __launch_bounds__(256) dwconv_kernel(const bf16* __restrict__ xd,
        const float* __restrict__ saw, const float* __restrict__ vecs,
        float* __restrict__ aggs){
    int nr = blockIdx.x;            // n*RC_+r
    int t  = blockIdx.y;
    int r  = nr % RC_;
    __shared__ float tile[9*TFRM];
    __shared__ float wsm[3][81];
    int tid = threadIdx.x;          // 256
    for (int i=tid;i<9*TFRM;i+=256) tile[i] = 0.f;
    if (tid < 81){
        wsm[0][tid]=saw[       r*81+tid];
        wsm[1][tid]=saw[2592 + r*81+tid];
        wsm[2][tid]=saw[5184 + r*81+tid];
    }
    __syncthreads();
    const bf16* base = xd + (size_t)nr*T_*HW_;
    for (int i=tid;i<9*HW_;i+=256){
        int kt = i/HW_, hw = i - kt*HW_;
        int tg = t - 4 + kt;
        if (tg>=0 && tg<T_){
            int h = hw/W_, w = hw - h*W_;
            tile[kt*TFRM + (h+3)*TPAD + (w+3)] = b2f(base[(size_t)tg*HW_ + hw]);
        }
    }
    __syncthreads();
    if (tid < HW_){
        int h = tid/W_, w = tid - h*W_;
        float w0=vecs[VWTS+0], w1=vecs[VWTS+1], w2v=vecs[VWTS+2];
        float cbias = w0*vecs[VSAB+r] + w1*vecs[VSAB+32+r] + w2v*vecs[VSAB+64+r];
        float bacc[3];
        #pragma unroll
        for (int br=0;br<3;br++){
            int d = br+1;
            float s = 0.f;
            #pragma unroll
            for (int kt=0;kt<9;kt++){
                const float* tb = &tile[kt*TFRM + (h+3-d)*TPAD + (w+3-d)];
                const float* wp = &wsm[br][kt*9];
                s += wp[0]*tb[0]          + wp[1]*tb[d]          + wp[2]*tb[2*d]
                   + wp[3]*tb[d*TPAD]     + wp[4]*tb[d*TPAD+d]   + wp[5]*tb[d*TPAD+2*d]
                   + wp[6]*tb[2*d*TPAD]   + wp[7]*tb[2*d*TPAD+d] + wp[8]*tb[2*d*TPAD+2*d];
            }
            bacc[br] = s;
        }
        float acc = cbias + w0*bacc[0] + w1*bacc[1] + w2v*bacc[2];
        aggs[(size_t)nr*T_*HW_ + (size_t)t*HW_ + tid] = acc;
    }
}

// ---------- final: conv_back (reg-resident agg) + gate * feat -> fp32 out ----------
__global__ void __launch_bounds__(256) final_kernel(const float* __restrict__ aggs,
                                                    const float* __restrict__ cbwf,
                                                    const float* __restrict__ feat,
                                                    float* __restrict__ out){
    int b = blockIdx.x, n = b/T_, t = b%T_;
    int c0 = blockIdx.y*128;
    int hw = threadIdx.x;
    if (hw >= HW_) return;
    float ra[RC_];
    #pragma unroll
    for (int r=0;r<RC_;r++)
        ra[r] = aggs[(((size_t)n*RC_+r)*T_ + t)*HW_ + hw];
    const float* fb = feat + (size_t)b*C_;
    for (int ci=0;ci<128;ci++){
        int c = c0+ci;
        const float* wr = cbwf + c*RC_;    // wave-uniform
        float a = 0.f;
        #pragma unroll
        for (int r=0;r<RC_;r++) a += wr[r]*ra[r];
        out[(((size_t)n*C_+c)*T_ + t)*HW_ + hw] = fb[c]*(sigm(a)-0.5f);
    }
}

extern "C" void kernel_launch(void* const* d_in, const int* in_sizes, int n_in,
                              void* d_out, int out_size, void* d_ws, size_t ws_size,
                              hipStream_t stream){
    const void* x      = d_in[0];
    const void* dcw2   = d_in[1];
    const void* dcw    = d_in[2];
    const void* cbw    = d_in[3];
    const void* w2     = d_in[4];
    const void* w4     = d_in[5];
    const void* wts    = d_in[6];
    const void* query  = d_in[7];
    const void* q_w    = d_in[8];
    const void* q_b    = d_in[9];
    const void* k_w    = d_in[10];
    const void* k_b    = d_in[11];
    const void* v_w    = d_in[12];
    const void* v_b    = d_in[13];
    const void* c_w    = d_in[14];
    const void* c_b    = d_in[15];
    const void* sa1w   = d_in[16];
    const void* sa1b   = d_in[17];
    const void* sa2w   = d_in[18];
    const void* sa2b   = d_in[19];
    const void* sa3w   = d_in[20];
    const void* sa3b   = d_in[21];
    float* out = (float*)d_out;

    // workspace layout — ~12.5 MB
    float* ws    = (float*)d_ws;
    int*   flag  = (int*)ws;               // 16
    float* qk    = ws + 16;                // 1024
    float* qp    = qk + 1024;              // 1024 (uses 512)
    float* pooled= qp + 1024;              // 98304
    float* mm    = pooled + 98304;         // 98304
    float* xq    = mm + 98304;             // 98304
    float* yq    = xq + 98304;             // 98304
    float* feat  = yq + 98304;             // 98304
    float* w2t   = feat + 98304;           // 262144
    float* vwt   = w2t + 262144;           // 262144
    float* cwt   = vwt + 262144;           // 262144
    float* dwt   = cwt + 262144;           // 16384
    float* cbwf  = dwt + 16384;            // 16384
    float* saw   = cbwf + 16384;           // 7936 (uses 7776)
    float* vecs  = saw + 7936;             // 2720
    float* aggs  = vecs + VECS_TOTAL;      // 1204224 fp32
    bf16*  xd    = (bf16*)(aggs + 1204224);// 1204224 bf16
    // xt (channel-last bf16 x) in first 38.5 MB of d_out; zpart (4x2.36 MB)
    // in the next 9.4 MB. Both fully consumed before final_kernel writes d_out.
    bf16*  xt    = (bf16*)d_out;
    float* zpart = (float*)(xt + (size_t)XTOT);

    probe_kernel<<<1, 64, 0, stream>>>(x, flag);
    prep_w2t_kernel<<<(C_*C_+255)/256, 256, 0, stream>>>(dcw2, w2t, flag);
    prep_misc_kernel<<<(PM_TOTAL+255)/256, 256, 0, stream>>>(
        dcw, cbw, sa1w, sa2w, sa3w, q_b, k_b, v_b, c_b, query,
        sa1b, sa2b, sa3b, w2, w4, wts, v_w, c_w,
        dwt, cbwf, saw, vecs, vwt, cwt, flag);
    cvt_tr_kernel<<<dim3(B_, C_/TCH), 256, 0, stream>>>(x, xt, flag);

    qproj1_kernel<<<C_, 64, 0, stream>>>(q_w, vecs, qp, flag);
    qproj2_kernel<<<9, 256, 0, stream>>>(k_w, vecs, qp, qk, flag);
    f1_kernel<<<B_, 512, 0, stream>>>(xt, qk, vecs, pooled, mm);
    proj_kernel<<<B_, C_, 0, stream>>>(pooled, mm, vwt, cwt, dcw2, vecs, xq, yq, flag);

    corr2gz_kernel<<<dim3(B_, 4), 512, 0, stream>>>(xt, yq, vecs, zpart);
    corr2f_kernel<<<dim3(B_, 4), 128, 0, stream>>>(zpart, w2t, feat);

    xdown_kernel<<<dim3(B_, 25), 256, 0, stream>>>(xt, dwt, xd);
    dwconv_kernel<<<dim3(N_*RC_, T_), 256, 0, stream>>>(xd, saw, vecs, aggs);
    final_kernel<<<dim3(B_, 4), 256, 0, stream>>>(aggs, cbwf, feat, out);
}

// Round 6
// 647.087 us; speedup vs baseline: 1.2361x; 1.0482x over previous
//
#include <hip/hip_runtime.h>
#include <hip/hip_bf16.h>

using bf16 = __hip_bfloat16;
typedef __attribute__((ext_vector_type(4))) unsigned short ushort4v;

#define N_  2
#define C_  512
#define T_  96
#define H_  14
#define W_  14
#define HW_ 196
#define RC_ 32
#define B_  (N_*T_)    // 192
#define SC_ (T_*HW_)   // 18816 elems per channel (input layout)
#define XTOT (N_*C_*T_*HW_)  // 19267584

// fp32 vec arena offsets
#define VQB   0
#define VKB   512
#define VVB   1024
#define VCB   1536
#define VQRY  2048
#define VSAB  2560   // 96 (3x32)
#define VW2   2688   // 6
#define VW4   2696   // 3
#define VWTS  2700   // 3
#define VECS_TOTAL 2720

__device__ __forceinline__ float b2f(bf16 v){ return __bfloat162float(v); }
__device__ __forceinline__ float u2f(unsigned short u){ return __uint_as_float(((unsigned)u)<<16); }
__device__ __forceinline__ float sigm(float x){ return 1.f/(1.f+__expf(-x)); }
__device__ __forceinline__ unsigned short f2bu(float f){
    bf16 b = __float2bfloat16(f);
    return *(unsigned short*)&b;
}

__device__ __forceinline__ float ldd(const void* p, size_t i, bool f32){
    if (f32) return ((const float*)p)[i];
    else     return b2f(((const bf16*)p)[i]);
}

// ---------- probe: fp32 vs bf16 inputs ----------
__global__ void probe_kernel(const void* __restrict__ x, int* __restrict__ flag){
    if (blockIdx.x==0 && threadIdx.x==0){
        const unsigned short* h = (const unsigned short*)x;
        int wild = 0;
        for (int i=0;i<128;i++){
            int e = (h[i] >> 7) & 0xFF;
            if (e < 100 || e > 150) wild++;
        }
        flag[0] = (wild > 16) ? 1 : 0;   // 1 => fp32 inputs
    }
}

// ---------- prep: down_conv2_w -> fp32 transposed  w2t[e][o] = W[o][e] ----------
__global__ void prep_w2t_kernel(const void* __restrict__ dcw2, float* __restrict__ w2t,
                                const int* __restrict__ flag){
    bool f32 = flag[0]!=0;
    int i = blockIdx.x*256 + threadIdx.x;
    if (i < C_*C_){
        int in = i / C_, out = i % C_;
        w2t[i] = ldd(dcw2, (size_t)out*C_ + in, f32);
    }
}

// ---------- prep: small weights -> fp32 arenas (+ v_w/c_w transposes) ----------
// NOTE: dwt is now a plain fp32 copy of down_conv_w, row-major [r][C].
#define PM_OLD (16384+16384+7776+512*5+96+6+3+3)
#define PM_TOTAL (PM_OLD + 262144 + 262144)
__global__ void prep_misc_kernel(const void* dcw, const void* cbw,
                                 const void* sa1w, const void* sa2w, const void* sa3w,
                                 const void* q_b, const void* k_b, const void* v_b,
                                 const void* c_b, const void* query,
                                 const void* sa1b, const void* sa2b, const void* sa3b,
                                 const void* w2, const void* w4, const void* wts,
                                 const void* v_w, const void* c_w,
                                 float* __restrict__ dwt, float* __restrict__ cbwf,
                                 float* __restrict__ saw, float* __restrict__ vecs,
                                 float* __restrict__ vwt, float* __restrict__ cwt,
                                 const int* __restrict__ flag){
    bool f32 = flag[0]!=0;
    int i = blockIdx.x*256 + threadIdx.x;
    if (i >= PM_TOTAL) return;
    if (i < 16384){ dwt[i] = ldd(dcw, i, f32); return; }   // identity copy [r][c]
    i -= 16384;
    if (i < 16384){ cbwf[i] = ldd(cbw, i, f32); return; }
    i -= 16384;
    if (i < 7776){
        const void* s = (i<2592)? sa1w : ((i<5184)? sa2w : sa3w);
        int j = (i<2592)? i : ((i<5184)? i-2592 : i-5184);
        saw[i] = ldd(s, j, f32); return;
    }
    i -= 7776;
    if (i < 512){ vecs[VQB +i] = ldd(q_b,  i, f32); return; } i -= 512;
    if (i < 512){ vecs[VKB +i] = ldd(k_b,  i, f32); return; } i -= 512;
    if (i < 512){ vecs[VVB +i] = ldd(v_b,  i, f32); return; } i -= 512;
    if (i < 512){ vecs[VCB +i] = ldd(c_b,  i, f32); return; } i -= 512;
    if (i < 512){ vecs[VQRY+i] = ldd(query,i, f32); return; } i -= 512;
    if (i < 96){
        const void* s = (i<32)? sa1b : ((i<64)? sa2b : sa3b);
        vecs[VSAB+i] = ldd(s, i&31, f32); return;
    }
    i -= 96;
    if (i < 6){ vecs[VW2+i] = ldd(w2, i, f32); return; } i -= 6;
    if (i < 3){ vecs[VW4+i] = ldd(w4, i, f32); return; } i -= 3;
    if (i < 3){ vecs[VWTS+i] = ldd(wts, i, f32); return; } i -= 3;
    if (i < 262144){ int r=i/C_, c=i%C_; vwt[i] = ldd(v_w, (size_t)c*C_+r, f32); return; }
    i -= 262144;
    { int r=i/C_, c=i%C_; cwt[i] = ldd(c_w, (size_t)c*C_+r, f32); }
}

// ---------- cvt_tr: x (n,c,t,l) -> xt (n,t,l,c) bf16, LDS-tiled transpose ----------
// load phase vectorized x4 (HW_=196 => 49 vec4 groups per channel-row)
#define TCH 128
__global__ void __launch_bounds__(256) cvt_tr_kernel(const void* __restrict__ x,
                                                     bf16* __restrict__ xt,
                                                     const int* __restrict__ flag){
    bool f32 = flag[0]!=0;
    int bt = blockIdx.x;               // n*T+t
    int n = bt / T_, t = bt % T_;
    int c0 = blockIdx.y * TCH;
    __shared__ bf16 tile[TCH*197];     // +1 elem pad per row
    int tid = threadIdx.x;
    const size_t ibase = (((size_t)n*C_ + c0)*T_ + t)*HW_;
    for (int i=tid; i<TCH*49; i+=256){
        int cr = i / 49, l4 = (i - cr*49)*4;
        size_t gi = ibase + (size_t)cr*SC_ + l4;     // 4-aligned (HW_,SC_ div by 4)
        bf16* dp = &tile[cr*197 + l4];
        if (f32){
            float4 v = *(const float4*)((const float*)x + gi);
            dp[0]=__float2bfloat16(v.x); dp[1]=__float2bfloat16(v.y);
            dp[2]=__float2bfloat16(v.z); dp[3]=__float2bfloat16(v.w);
        } else {
            ushort4v u = *(const ushort4v*)((const bf16*)x + gi);
            #pragma unroll
            for (int k=0;k<4;k++) *(unsigned short*)&dp[k] = u[k];
        }
    }
    __syncthreads();
    bf16* obase = xt + (size_t)bt*HW_*C_ + c0;
    for (int i=tid; i<HW_*TCH/4; i+=256){
        int l = i >> 5, cg = (i & 31)*4;
        ushort4v u;
        #pragma unroll
        for (int k=0;k<4;k++) u[k] = *(unsigned short*)&tile[(cg+k)*197 + l];
        *(ushort4v*)(obase + (size_t)l*C_ + cg) = u;
    }
}

// ---------- K1a: qp[c] = (query . q_w[c,:] + q_b[c]) * C^-0.5 ----------
__global__ void __launch_bounds__(64) qproj1_kernel(const void* __restrict__ q_w,
        const float* __restrict__ vecs, float* __restrict__ qp,
        const int* __restrict__ flag){
    bool f32 = flag[0]!=0;
    int c = blockIdx.x;
    int lane = threadIdx.x;
    float acc = 0.f;
    #pragma unroll
    for (int i=lane;i<C_;i+=64)
        acc += vecs[VQRY+i] * ldd(q_w, (size_t)c*C_+i, f32);
    #pragma unroll
    for (int off=32; off>0; off>>=1) acc += __shfl_down(acc, off);
    if (lane==0) qp[c] = (acc + vecs[VQB+c]) * 0.044194173824159216f;   // 512^-0.5
}

// ---------- K1b: qk[c] = sum_i qp[i]*k_w[i*C+c];  qk[C] = qp . k_b ----------
__global__ void __launch_bounds__(256) qproj2_kernel(const void* __restrict__ k_w,
        const float* __restrict__ vecs, const float* __restrict__ qp,
        float* __restrict__ qk_out, const int* __restrict__ flag){
    bool f32 = flag[0]!=0;
    __shared__ float sh[256];
    int tid = threadIdx.x;
    if (blockIdx.x < 8){
        int c = blockIdx.x*64 + (tid&63);
        int isub = tid>>6;
        float acc = 0.f;
        for (int i=isub*128; i<isub*128+128; i++)
            acc += qp[i] * ldd(k_w, (size_t)i*C_ + c, f32);
        sh[tid] = acc;
        __syncthreads();
        if (tid < 64)
            qk_out[c] = sh[tid] + sh[tid+64] + sh[tid+128] + sh[tid+192];
    } else {
        float acc = 0.f;
        for (int i=tid;i<C_;i+=256) acc += qp[i]*vecs[VKB+i];
        sh[tid] = acc;
        __syncthreads();
        if (tid==0){
            float d=0.f;
            for (int i=0;i<256;i++) d += sh[i];
            qk_out[C_] = d;
        }
    }
}

// ---------- F1: logits + softmax + pooled/mm, all wave-per-row coalesced ----------
__global__ void __launch_bounds__(512) f1_kernel(const bf16* __restrict__ xt,
        const float* __restrict__ qk, const float* __restrict__ vecs,
        float* __restrict__ pooled, float* __restrict__ mm){
    int b = blockIdx.x;
    __shared__ float sm[HW_];
    __shared__ float red[2];
    __shared__ float r8[8][C_];
    int tid = threadIdx.x, wave = tid>>6, lane = tid&63;
    float qkr[8];
    #pragma unroll
    for (int k=0;k<4;k++){ qkr[k] = qk[lane*4+k]; qkr[4+k] = qk[256+lane*4+k]; }
    float qkC = qk[C_];
    const bf16* fbase = xt + (size_t)b*HW_*C_;
    for (int l=wave; l<HW_; l+=8){
        const bf16* row = fbase + (size_t)l*C_;
        ushort4v u1 = *(const ushort4v*)(row + lane*4);
        ushort4v u2 = *(const ushort4v*)(row + 256 + lane*4);
        float a = 0.f;
        #pragma unroll
        for (int k=0;k<4;k++) a += qkr[k]*u2f(u1[k]) + qkr[4+k]*u2f(u2[k]);
        #pragma unroll
        for (int off=32; off>0; off>>=1) a += __shfl_down(a, off);
        if (lane==0) sm[l] = a + qkC;
    }
    __syncthreads();
    if (tid < 64){
        float m = -1e30f;
        for (int l=tid; l<HW_; l+=64) m = fmaxf(m, sm[l]);
        #pragma unroll
        for (int off=32; off>0; off>>=1) m = fmaxf(m, __shfl_down(m, off));
        if (tid==0) red[0] = m;
    }
    __syncthreads();
    if (tid < HW_) sm[tid] = __expf(sm[tid]-red[0]);
    __syncthreads();
    if (tid < 64){
        float s = 0.f;
        for (int l=tid; l<HW_; l+=64) s += sm[l];
        #pragma unroll
        for (int off=32; off>0; off>>=1) s += __shfl_down(s, off);
        if (tid==0) red[1] = 1.f/s;
    }
    __syncthreads();
    if (tid < HW_) sm[tid] *= red[1];
    __syncthreads();
    // pass 2: per-lane 8-channel accumulators over wave's row subset
    float sa[8], pa[8], ma[8];
    #pragma unroll
    for (int k=0;k<8;k++){ sa[k]=0.f; pa[k]=0.f; ma[k]=-1e30f; }
    for (int l=wave; l<HW_; l+=8){
        const bf16* row = fbase + (size_t)l*C_;
        ushort4v u1 = *(const ushort4v*)(row + lane*4);
        ushort4v u2 = *(const ushort4v*)(row + 256 + lane*4);
        float smv = sm[l];
        #pragma unroll
        for (int k=0;k<4;k++){
            float v1 = u2f(u1[k]), v2 = u2f(u2[k]);
            sa[k]   += v1; ma[k]   = fmaxf(ma[k],  v1); pa[k]   += smv*v1;
            sa[4+k] += v2; ma[4+k] = fmaxf(ma[4+k],v2); pa[4+k] += smv*v2;
        }
    }
    int c1 = lane*4, c2 = 256+lane*4;
    #pragma unroll
    for (int k=0;k<4;k++){ r8[wave][c1+k]=pa[k]; r8[wave][c2+k]=pa[4+k]; }
    __syncthreads();
    int c = tid;
    float pltot = 0.f;
    #pragma unroll
    for (int w=0;w<8;w++) pltot += r8[w][c];
    __syncthreads();
    #pragma unroll
    for (int k=0;k<4;k++){ r8[wave][c1+k]=sa[k]; r8[wave][c2+k]=sa[4+k]; }
    __syncthreads();
    float stot = 0.f;
    #pragma unroll
    for (int w=0;w<8;w++) stot += r8[w][c];
    __syncthreads();
    #pragma unroll
    for (int k=0;k<4;k++){ r8[wave][c1+k]=ma[k]; r8[wave][c2+k]=ma[4+k]; }
    __syncthreads();
    float mtot = -1e30f;
    #pragma unroll
    for (int w=0;w<8;w++) mtot = fmaxf(mtot, r8[w][c]);
    pooled[(size_t)b*C_+c] = pltot;
    float w40=vecs[VW4+0], w41=vecs[VW4+1];
    mm[(size_t)b*C_+c] = stot*(1.f/HW_)*w40 + mtot*w41;
}

// ---------- proj: v-proj -> c-proj -> xq -> yq (all coalesced) ----------
__global__ void __launch_bounds__(512) proj_kernel(const float* __restrict__ pooled,
        const float* __restrict__ mm, const float* __restrict__ vwt,
        const float* __restrict__ cwt, const void* __restrict__ dcw2,
        const float* __restrict__ vecs, float* __restrict__ xq,
        float* __restrict__ yq, const int* __restrict__ flag){
    bool f32 = flag[0]!=0;
    int b = blockIdx.x, c = threadIdx.x;       // 512 threads
    __shared__ float p_s[C_];
    __shared__ float pre_s[C_];
    __shared__ float xq_s[C_];
    p_s[c] = pooled[(size_t)b*C_ + c];
    __syncthreads();
    float pre = vecs[VVB+c];
    for (int i=0;i<C_;i++) pre += p_s[i]*vwt[(size_t)i*C_+c];
    pre_s[c] = pre;
    __syncthreads();
    float att = vecs[VCB+c];
    for (int i=0;i<C_;i++) att += pre_s[i]*cwt[(size_t)i*C_+c];
    float xqv = mm[(size_t)b*C_+c] + vecs[VW4+2]*att;
    xq[(size_t)b*C_+c] = xqv;
    xq_s[c] = xqv;
    __syncthreads();
    float yqv = 0.f;
    for (int i=0;i<C_;i++) yqv += xq_s[i]*ldd(dcw2, (size_t)i*C_+c, f32);
    yq[(size_t)b*C_+c] = yqv;
}

// ---------- corr2gz: fused gates + z-partials, frame-quarter blocks ----------
#define QROWS 49
#define B6C   (B_*6*C_)   // 589824
__global__ void __launch_bounds__(512) corr2gz_kernel(const bf16* __restrict__ xt,
        const float* __restrict__ yq, const float* __restrict__ vecs,
        float* __restrict__ zpart){
    const int offs[6] = {-3,-2,-1,1,2,3};
    int frame = blockIdx.x;            // n*T_ + t'
    int qq = blockIdx.y;               // row quarter
    int n = frame / T_, tp = frame % T_;
    int l0 = qq*QROWS;
    __shared__ bf16 xs[QROWS*C_];      // 50176 B
    __shared__ float a_s[6][QROWS];
    int tid = threadIdx.x, lane = tid&63, wave = tid>>6;
    // stage 49 rows, coalesced ushort4
    const ushort4v* src = (const ushort4v*)(xt + ((size_t)frame*HW_ + l0)*C_);
    ushort4v* dst = (ushort4v*)xs;
    for (int i=tid; i<QROWS*C_/4; i+=512) dst[i] = src[i];
    // target validity + yq registers + weights
    bool val[6]; float w2r[6]; float yqr[6][8];
    #pragma unroll
    for (int jj=0;jj<6;jj++){
        int tt = tp - offs[jj];
        val[jj] = (tt>=0 && tt<T_);
        w2r[jj] = vecs[VW2+jj];
        if (val[jj]){
            const float* yb = yq + (size_t)(n*T_+tt)*C_;
            #pragma unroll
            for (int k=0;k<4;k++){ yqr[jj][k]=yb[lane*4+k]; yqr[jj][4+k]=yb[256+lane*4+k]; }
        } else {
            #pragma unroll
            for (int k=0;k<8;k++) yqr[jj][k]=0.f;
        }
    }
    __syncthreads();
    // gates: wave-per-row, 6 targets at once
    for (int li=wave; li<QROWS; li+=8){
        ushort4v u1 = *(const ushort4v*)(xs + li*C_ + lane*4);
        ushort4v u2 = *(const ushort4v*)(xs + li*C_ + 256 + lane*4);
        float xf[8];
        #pragma unroll
        for (int k=0;k<4;k++){ xf[k]=u2f(u1[k]); xf[4+k]=u2f(u2[k]); }
        float a[6];
        #pragma unroll
        for (int jj=0;jj<6;jj++){
            float s=0.f;
            #pragma unroll
            for (int k=0;k<8;k++) s += yqr[jj][k]*xf[k];
            a[jj]=s;
        }
        #pragma unroll
        for (int off=32; off>0; off>>=1){
            #pragma unroll
            for (int jj=0;jj<6;jj++) a[jj] += __shfl_down(a[jj], off);
        }
        if (lane==0){
            #pragma unroll
            for (int jj=0;jj<6;jj++)
                a_s[jj][li] = val[jj] ? w2r[jj]*(sigm(w2r[jj]*a[jj])-0.5f) : 0.f;
        }
    }
    __syncthreads();
    // z-partials: thread-per-e over the 49 staged rows
    int e = tid;
    float acc[6] = {0.f,0.f,0.f,0.f,0.f,0.f};
    for (int li=0; li<QROWS; ++li){
        float xv = b2f(xs[li*C_ + e]);
        #pragma unroll
        for (int jj=0;jj<6;jj++) acc[jj] += a_s[jj][li]*xv;
    }
    #pragma unroll
    for (int jj=0;jj<6;jj++){
        if (val[jj]){
            int b = n*T_ + (tp - offs[jj]);
            zpart[(size_t)qq*B6C + ((size_t)b*6+jj)*C_ + e] = acc[jj];
        }
    }
}

// ---------- corr2f: z = sum(valid zparts); feat[b][c] = sum_e w2t[e][c]*z[e] ----------
__global__ void __launch_bounds__(128) corr2f_kernel(const float* __restrict__ zpart,
        const float* __restrict__ w2t, float* __restrict__ feat){
    const int offs[6] = {-3,-2,-1,1,2,3};
    int b = blockIdx.x, c0 = blockIdx.y*128;
    int t = b % T_;
    int tid = threadIdx.x;
    __shared__ float z_s[C_];
    for (int e=tid; e<C_; e+=128){
        float s = 0.f;
        #pragma unroll
        for (int jj=0;jj<6;jj++){
            int tj = t + offs[jj];
            if (tj<0 || tj>=T_) continue;
            const float* zp = zpart + ((size_t)b*6+jj)*C_ + e;
            s += zp[0] + zp[B6C] + zp[2*B6C] + zp[3*(size_t)B6C];
        }
        z_s[e] = s;
    }
    __syncthreads();
    int c = c0 + tid;
    float acc = 0.f;
    for (int e=0;e<C_;e++) acc += w2t[(size_t)e*C_+c]*z_s[e];
    feat[(size_t)b*C_+c] = acc;
}

// ---------- xdown: x_down = down_conv_w @ x, padded-LDS + float4 weight rows ----------
#define XPAD 8
#define XROW (C_+XPAD)   // 520
__global__ void __launch_bounds__(256) xdown_kernel(const bf16* __restrict__ xt,
                                                    const float* __restrict__ dwt,
                                                    bf16* __restrict__ xd){
    int b = blockIdx.x, n=b/T_, t=b%T_;
    int l0 = blockIdx.y*8;
    int nl = HW_ - l0; if (nl > 8) nl = 8;
    __shared__ bf16 xs[8*XROW];
    int tid = threadIdx.x;
    const bf16* fbase = xt + (size_t)b*HW_*C_ + (size_t)l0*C_;
    for (int i=tid; i<nl*(C_/4); i+=256){
        int row = i >> 7, gc = (i & 127)*4;
        *(ushort4v*)(xs + row*XROW + gc) = *(const ushort4v*)(fbase + (size_t)row*C_ + gc);
    }
    __syncthreads();
    int r = tid>>3, ls = tid&7;
    if (ls < nl){
        float acc = 0.f;
        const bf16* xr = xs + ls*XROW;
        const float* wr = dwt + (size_t)r*C_;   // row-major weights: float4-able
        #pragma unroll 4
        for (int c4=0; c4<C_; c4+=4){
            ushort4v u = *(const ushort4v*)(xr + c4);
            float4 w = *(const float4*)(wr + c4);
            acc += w.x*u2f(u[0]) + w.y*u2f(u[1])
                 + w.z*u2f(u[2]) + w.w*u2f(u[3]);
        }
        xd[(((size_t)n*RC_+r)*T_ + t)*HW_ + l0 + ls] = __float2bfloat16(acc);
    }
}

// ---------- dwconv: padded-tile version, one (n,r,t) per block ----------
#define TPAD 21
#define TROW 20
#define TFRM (TROW*TPAD)   // 420
__global__ void __launch_bounds__(256) dwconv_kernel(const bf16* __restrict__ xd,
        const float* __restrict__ saw, const float* __restrict__ vecs,
        float* __restrict__ aggs){
    int nr = blockIdx.x;            // n*RC_+r
    int t  = blockIdx.y;
    int r  = nr % RC_;
    __shared__ float tile[9*TFRM];
    __shared__ float wsm[3][81];
    int tid = threadIdx.x;          // 256
    for (int i=tid;i<9*TFRM;i+=256) tile[i] = 0.f;
    if (tid < 81){
        wsm[0][tid]=saw[       r*81+tid];
        wsm[1][tid]=saw[2592 + r*81+tid];
        wsm[2][tid]=saw[5184 + r*81+tid];
    }
    __syncthreads();
    const bf16* base = xd + (size_t)nr*T_*HW_;
    for (int i=tid;i<9*HW_;i+=256){
        int kt = i/HW_, hw = i - kt*HW_;
        int tg = t - 4 + kt;
        if (tg>=0 && tg<T_){
            int h = hw/W_, w = hw - h*W_;
            tile[kt*TFRM + (h+3)*TPAD + (w+3)] = b2f(base[(size_t)tg*HW_ + hw]);
        }
    }
    __syncthreads();
    if (tid < HW_){
        int h = tid/W_, w = tid - h*W_;
        float w0=vecs[VWTS+0], w1=vecs[VWTS+1], w2v=vecs[VWTS+2];
        float cbias = w0*vecs[VSAB+r] + w1*vecs[VSAB+32+r] + w2v*vecs[VSAB+64+r];
        float bacc[3];
        #pragma unroll
        for (int br=0;br<3;br++){
            int d = br+1;
            float s = 0.f;
            #pragma unroll
            for (int kt=0;kt<9;kt++){
                const float* tb = &tile[kt*TFRM + (h+3-d)*TPAD + (w+3-d)];
                const float* wp = &wsm[br][kt*9];
                s += wp[0]*tb[0]          + wp[1]*tb[d]          + wp[2]*tb[2*d]
                   + wp[3]*tb[d*TPAD]     + wp[4]*tb[d*TPAD+d]   + wp[5]*tb[d*TPAD+2*d]
                   + wp[6]*tb[2*d*TPAD]   + wp[7]*tb[2*d*TPAD+d] + wp[8]*tb[2*d*TPAD+2*d];
            }
            bacc[br] = s;
        }
        float acc = cbias + w0*bacc[0] + w1*bacc[1] + w2v*bacc[2];
        aggs[(size_t)nr*T_*HW_ + (size_t)t*HW_ + tid] = acc;
    }
}

// ---------- final: conv_back (reg-resident agg) + gate * feat -> fp32 out ----------
__global__ void __launch_bounds__(256) final_kernel(const float* __restrict__ aggs,
                                                    const float* __restrict__ cbwf,
                                                    const float* __restrict__ feat,
                                                    float* __restrict__ out){
    int b = blockIdx.x, n = b/T_, t = b%T_;
    int c0 = blockIdx.y*128;
    int hw = threadIdx.x;
    if (hw >= HW_) return;
    float ra[RC_];
    #pragma unroll
    for (int r=0;r<RC_;r++)
        ra[r] = aggs[(((size_t)n*RC_+r)*T_ + t)*HW_ + hw];
    const float* fb = feat + (size_t)b*C_;
    for (int ci=0;ci<128;ci++){
        int c = c0+ci;
        const float* wr = cbwf + c*RC_;    // wave-uniform
        float a = 0.f;
        #pragma unroll
        for (int r=0;r<RC_;r++) a += wr[r]*ra[r];
        out[(((size_t)n*C_+c)*T_ + t)*HW_ + hw] = fb[c]*(sigm(a)-0.5f);
    }
}

extern "C" void kernel_launch(void* const* d_in, const int* in_sizes, int n_in,
                              void* d_out, int out_size, void* d_ws, size_t ws_size,
                              hipStream_t stream){
    const void* x      = d_in[0];
    const void* dcw2   = d_in[1];
    const void* dcw    = d_in[2];
    const void* cbw    = d_in[3];
    const void* w2     = d_in[4];
    const void* w4     = d_in[5];
    const void* wts    = d_in[6];
    const void* query  = d_in[7];
    const void* q_w    = d_in[8];
    const void* q_b    = d_in[9];
    const void* k_w    = d_in[10];
    const void* k_b    = d_in[11];
    const void* v_w    = d_in[12];
    const void* v_b    = d_in[13];
    const void* c_w    = d_in[14];
    const void* c_b    = d_in[15];
    const void* sa1w   = d_in[16];
    const void* sa1b   = d_in[17];
    const void* sa2w   = d_in[18];
    const void* sa2b   = d_in[19];
    const void* sa3w   = d_in[20];
    const void* sa3b   = d_in[21];
    float* out = (float*)d_out;

    // workspace layout — ~12.5 MB
    float* ws    = (float*)d_ws;
    int*   flag  = (int*)ws;               // 16
    float* qk    = ws + 16;                // 1024
    float* qp    = qk + 1024;              // 1024 (uses 512)
    float* pooled= qp + 1024;              // 98304
    float* mm    = pooled + 98304;         // 98304
    float* xq    = mm + 98304;             // 98304
    float* yq    = xq + 98304;             // 98304
    float* feat  = yq + 98304;             // 98304
    float* w2t   = feat + 98304;           // 262144
    float* vwt   = w2t + 262144;           // 262144
    float* cwt   = vwt + 262144;           // 262144
    float* dwt   = cwt + 262144;           // 16384
    float* cbwf  = dwt + 16384;            // 16384
    float* saw   = cbwf + 16384;           // 7936 (uses 7776)
    float* vecs  = saw + 7936;             // 2720
    float* aggs  = vecs + VECS_TOTAL;      // 1204224 fp32
    bf16*  xd    = (bf16*)(aggs + 1204224);// 1204224 bf16
    // xt (channel-last bf16 x) in first 38.5 MB of d_out; zpart (4x2.36 MB)
    // in the next 9.4 MB. Both fully consumed before final_kernel writes d_out.
    bf16*  xt    = (bf16*)d_out;
    float* zpart = (float*)(xt + (size_t)XTOT);

    probe_kernel<<<1, 64, 0, stream>>>(x, flag);
    prep_w2t_kernel<<<(C_*C_+255)/256, 256, 0, stream>>>(dcw2, w2t, flag);
    prep_misc_kernel<<<(PM_TOTAL+255)/256, 256, 0, stream>>>(
        dcw, cbw, sa1w, sa2w, sa3w, q_b, k_b, v_b, c_b, query,
        sa1b, sa2b, sa3b, w2, w4, wts, v_w, c_w,
        dwt, cbwf, saw, vecs, vwt, cwt, flag);
    cvt_tr_kernel<<<dim3(B_, C_/TCH), 256, 0, stream>>>(x, xt, flag);

    qproj1_kernel<<<C_, 64, 0, stream>>>(q_w, vecs, qp, flag);
    qproj2_kernel<<<9, 256, 0, stream>>>(k_w, vecs, qp, qk, flag);
    f1_kernel<<<B_, 512, 0, stream>>>(xt, qk, vecs, pooled, mm);
    proj_kernel<<<B_, C_, 0, stream>>>(pooled, mm, vwt, cwt, dcw2, vecs, xq, yq, flag);

    corr2gz_kernel<<<dim3(B_, 4), 512, 0, stream>>>(xt, yq, vecs, zpart);
    corr2f_kernel<<<dim3(B_, 4), 128, 0, stream>>>(zpart, w2t, feat);

    xdown_kernel<<<dim3(B_, 25), 256, 0, stream>>>(xt, dwt, xd);
    dwconv_kernel<<<dim3(N_*RC_, T_), 256, 0, stream>>>(xd, saw, vecs, aggs);
    final_kernel<<<dim3(B_, 4), 256, 0, stream>>>(aggs, cbwf, feat, out);
}

// Round 7
// 637.933 us; speedup vs baseline: 1.2539x; 1.0143x over previous
//
#include <hip/hip_runtime.h>
#include <hip/hip_bf16.h>

using bf16 = __hip_bfloat16;
typedef __attribute__((ext_vector_type(4))) unsigned short ushort4v;

#define N_  2
#define C_  512
#define T_  96
#define H_  14
#define W_  14
#define HW_ 196
#define RC_ 32
#define B_  (N_*T_)    // 192
#define SC_ (T_*HW_)   // 18816 elems per channel (input layout)
#define XTOT (N_*C_*T_*HW_)  // 19267584

// fp32 vec arena offsets
#define VQB   0
#define VKB   512
#define VVB   1024
#define VCB   1536
#define VQRY  2048
#define VSAB  2560   // 96 (3x32)
#define VW2   2688   // 6
#define VW4   2696   // 3
#define VWTS  2700   // 3
#define VECS_TOTAL 2720

__device__ __forceinline__ float b2f(bf16 v){ return __bfloat162float(v); }
__device__ __forceinline__ float u2f(unsigned short u){ return __uint_as_float(((unsigned)u)<<16); }
__device__ __forceinline__ float sigm(float x){ return 1.f/(1.f+__expf(-x)); }
__device__ __forceinline__ unsigned short f2bu(float f){
    bf16 b = __float2bfloat16(f);
    return *(unsigned short*)&b;
}

__device__ __forceinline__ float ldd(const void* p, size_t i, bool f32){
    if (f32) return ((const float*)p)[i];
    else     return b2f(((const bf16*)p)[i]);
}

// ---------- probe: fp32 vs bf16 inputs ----------
__global__ void probe_kernel(const void* __restrict__ x, int* __restrict__ flag){
    if (blockIdx.x==0 && threadIdx.x==0){
        const unsigned short* h = (const unsigned short*)x;
        int wild = 0;
        for (int i=0;i<128;i++){
            int e = (h[i] >> 7) & 0xFF;
            if (e < 100 || e > 150) wild++;
        }
        flag[0] = (wild > 16) ? 1 : 0;   // 1 => fp32 inputs
    }
}

// ---------- prep: down_conv2_w -> fp32 transposed  w2t[e][o] = W[o][e] ----------
__global__ void prep_w2t_kernel(const void* __restrict__ dcw2, float* __restrict__ w2t,
                                const int* __restrict__ flag){
    bool f32 = flag[0]!=0;
    int i = blockIdx.x*256 + threadIdx.x;
    if (i < C_*C_){
        int in = i / C_, out = i % C_;
        w2t[i] = ldd(dcw2, (size_t)out*C_ + in, f32);
    }
}

// ---------- prep: small weights -> fp32 arenas (+ v_w/c_w transposes) ----------
// dwt is a plain fp32 copy of down_conv_w, row-major [r][C].
#define PM_OLD (16384+16384+7776+512*5+96+6+3+3)
#define PM_TOTAL (PM_OLD + 262144 + 262144)
__global__ void prep_misc_kernel(const void* dcw, const void* cbw,
                                 const void* sa1w, const void* sa2w, const void* sa3w,
                                 const void* q_b, const void* k_b, const void* v_b,
                                 const void* c_b, const void* query,
                                 const void* sa1b, const void* sa2b, const void* sa3b,
                                 const void* w2, const void* w4, const void* wts,
                                 const void* v_w, const void* c_w,
                                 float* __restrict__ dwt, float* __restrict__ cbwf,
                                 float* __restrict__ saw, float* __restrict__ vecs,
                                 float* __restrict__ vwt, float* __restrict__ cwt,
                                 const int* __restrict__ flag){
    bool f32 = flag[0]!=0;
    int i = blockIdx.x*256 + threadIdx.x;
    if (i >= PM_TOTAL) return;
    if (i < 16384){ dwt[i] = ldd(dcw, i, f32); return; }   // identity copy [r][c]
    i -= 16384;
    if (i < 16384){ cbwf[i] = ldd(cbw, i, f32); return; }
    i -= 16384;
    if (i < 7776){
        const void* s = (i<2592)? sa1w : ((i<5184)? sa2w : sa3w);
        int j = (i<2592)? i : ((i<5184)? i-2592 : i-5184);
        saw[i] = ldd(s, j, f32); return;
    }
    i -= 7776;
    if (i < 512){ vecs[VQB +i] = ldd(q_b,  i, f32); return; } i -= 512;
    if (i < 512){ vecs[VKB +i] = ldd(k_b,  i, f32); return; } i -= 512;
    if (i < 512){ vecs[VVB +i] = ldd(v_b,  i, f32); return; } i -= 512;
    if (i < 512){ vecs[VCB +i] = ldd(c_b,  i, f32); return; } i -= 512;
    if (i < 512){ vecs[VQRY+i] = ldd(query,i, f32); return; } i -= 512;
    if (i < 96){
        const void* s = (i<32)? sa1b : ((i<64)? sa2b : sa3b);
        vecs[VSAB+i] = ldd(s, i&31, f32); return;
    }
    i -= 96;
    if (i < 6){ vecs[VW2+i] = ldd(w2, i, f32); return; } i -= 6;
    if (i < 3){ vecs[VW4+i] = ldd(w4, i, f32); return; } i -= 3;
    if (i < 3){ vecs[VWTS+i] = ldd(wts, i, f32); return; } i -= 3;
    if (i < 262144){ int r=i/C_, c=i%C_; vwt[i] = ldd(v_w, (size_t)c*C_+r, f32); return; }
    i -= 262144;
    { int r=i/C_, c=i%C_; cwt[i] = ldd(c_w, (size_t)c*C_+r, f32); }
}

// ---------- cvt_tr: x (n,c,t,l) -> xt (n,t,l,c) bf16, LDS-tiled transpose ----------
#define TCH 128
__global__ void __launch_bounds__(256) cvt_tr_kernel(const void* __restrict__ x,
                                                     bf16* __restrict__ xt,
                                                     const int* __restrict__ flag){
    bool f32 = flag[0]!=0;
    int bt = blockIdx.x;               // n*T+t
    int n = bt / T_, t = bt % T_;
    int c0 = blockIdx.y * TCH;
    __shared__ bf16 tile[TCH*197];     // +1 elem pad per row
    int tid = threadIdx.x;
    const size_t ibase = (((size_t)n*C_ + c0)*T_ + t)*HW_;
    for (int i=tid; i<TCH*49; i+=256){
        int cr = i / 49, l4 = (i - cr*49)*4;
        size_t gi = ibase + (size_t)cr*SC_ + l4;     // 4-aligned (HW_,SC_ div by 4)
        bf16* dp = &tile[cr*197 + l4];
        if (f32){
            float4 v = *(const float4*)((const float*)x + gi);
            dp[0]=__float2bfloat16(v.x); dp[1]=__float2bfloat16(v.y);
            dp[2]=__float2bfloat16(v.z); dp[3]=__float2bfloat16(v.w);
        } else {
            ushort4v u = *(const ushort4v*)((const bf16*)x + gi);
            #pragma unroll
            for (int k=0;k<4;k++) *(unsigned short*)&dp[k] = u[k];
        }
    }
    __syncthreads();
    bf16* obase = xt + (size_t)bt*HW_*C_ + c0;
    for (int i=tid; i<HW_*TCH/4; i+=256){
        int l = i >> 5, cg = (i & 31)*4;
        ushort4v u;
        #pragma unroll
        for (int k=0;k<4;k++) u[k] = *(unsigned short*)&tile[(cg+k)*197 + l];
        *(ushort4v*)(obase + (size_t)l*C_ + cg) = u;
    }
}

// ---------- K1a: qp[c] = (query . q_w[c,:] + q_b[c]) * C^-0.5 ----------
__global__ void __launch_bounds__(64) qproj1_kernel(const void* __restrict__ q_w,
        const float* __restrict__ vecs, float* __restrict__ qp,
        const int* __restrict__ flag){
    bool f32 = flag[0]!=0;
    int c = blockIdx.x;
    int lane = threadIdx.x;
    float acc = 0.f;
    #pragma unroll
    for (int i=lane;i<C_;i+=64)
        acc += vecs[VQRY+i] * ldd(q_w, (size_t)c*C_+i, f32);
    #pragma unroll
    for (int off=32; off>0; off>>=1) acc += __shfl_down(acc, off);
    if (lane==0) qp[c] = (acc + vecs[VQB+c]) * 0.044194173824159216f;   // 512^-0.5
}

// ---------- K1b: qk[c] = sum_i qp[i]*k_w[i*C+c];  qk[C] = qp . k_b ----------
__global__ void __launch_bounds__(256) qproj2_kernel(const void* __restrict__ k_w,
        const float* __restrict__ vecs, const float* __restrict__ qp,
        float* __restrict__ qk_out, const int* __restrict__ flag){
    bool f32 = flag[0]!=0;
    __shared__ float sh[256];
    int tid = threadIdx.x;
    if (blockIdx.x < 8){
        int c = blockIdx.x*64 + (tid&63);
        int isub = tid>>6;
        float acc = 0.f;
        for (int i=isub*128; i<isub*128+128; i++)
            acc += qp[i] * ldd(k_w, (size_t)i*C_ + c, f32);
        sh[tid] = acc;
        __syncthreads();
        if (tid < 64)
            qk_out[c] = sh[tid] + sh[tid+64] + sh[tid+128] + sh[tid+192];
    } else {
        float acc = 0.f;
        for (int i=tid;i<C_;i+=256) acc += qp[i]*vecs[VKB+i];
        sh[tid] = acc;
        __syncthreads();
        if (tid==0){
            float d=0.f;
            for (int i=0;i<256;i++) d += sh[i];
            qk_out[C_] = d;
        }
    }
}

// ---------- F1: logits + softmax + pooled/mm, all wave-per-row coalesced ----------
__global__ void __launch_bounds__(512) f1_kernel(const bf16* __restrict__ xt,
        const float* __restrict__ qk, const float* __restrict__ vecs,
        float* __restrict__ pooled, float* __restrict__ mm){
    int b = blockIdx.x;
    __shared__ float sm[HW_];
    __shared__ float red[2];
    __shared__ float r8[8][C_];
    int tid = threadIdx.x, wave = tid>>6, lane = tid&63;
    float qkr[8];
    #pragma unroll
    for (int k=0;k<4;k++){ qkr[k] = qk[lane*4+k]; qkr[4+k] = qk[256+lane*4+k]; }
    float qkC = qk[C_];
    const bf16* fbase = xt + (size_t)b*HW_*C_;
    for (int l=wave; l<HW_; l+=8){
        const bf16* row = fbase + (size_t)l*C_;
        ushort4v u1 = *(const ushort4v*)(row + lane*4);
        ushort4v u2 = *(const ushort4v*)(row + 256 + lane*4);
        float a = 0.f;
        #pragma unroll
        for (int k=0;k<4;k++) a += qkr[k]*u2f(u1[k]) + qkr[4+k]*u2f(u2[k]);
        #pragma unroll
        for (int off=32; off>0; off>>=1) a += __shfl_down(a, off);
        if (lane==0) sm[l] = a + qkC;
    }
    __syncthreads();
    if (tid < 64){
        float m = -1e30f;
        for (int l=tid; l<HW_; l+=64) m = fmaxf(m, sm[l]);
        #pragma unroll
        for (int off=32; off>0; off>>=1) m = fmaxf(m, __shfl_down(m, off));
        if (tid==0) red[0] = m;
    }
    __syncthreads();
    if (tid < HW_) sm[tid] = __expf(sm[tid]-red[0]);
    __syncthreads();
    if (tid < 64){
        float s = 0.f;
        for (int l=tid; l<HW_; l+=64) s += sm[l];
        #pragma unroll
        for (int off=32; off>0; off>>=1) s += __shfl_down(s, off);
        if (tid==0) red[1] = 1.f/s;
    }
    __syncthreads();
    if (tid < HW_) sm[tid] *= red[1];
    __syncthreads();
    // pass 2: per-lane 8-channel accumulators over wave's row subset
    float sa[8], pa[8], ma[8];
    #pragma unroll
    for (int k=0;k<8;k++){ sa[k]=0.f; pa[k]=0.f; ma[k]=-1e30f; }
    for (int l=wave; l<HW_; l+=8){
        const bf16* row = fbase + (size_t)l*C_;
        ushort4v u1 = *(const ushort4v*)(row + lane*4);
        ushort4v u2 = *(const ushort4v*)(row + 256 + lane*4);
        float smv = sm[l];
        #pragma unroll
        for (int k=0;k<4;k++){
            float v1 = u2f(u1[k]), v2 = u2f(u2[k]);
            sa[k]   += v1; ma[k]   = fmaxf(ma[k],  v1); pa[k]   += smv*v1;
            sa[4+k] += v2; ma[4+k] = fmaxf(ma[4+k],v2); pa[4+k] += smv*v2;
        }
    }
    int c1 = lane*4, c2 = 256+lane*4;
    #pragma unroll
    for (int k=0;k<4;k++){ r8[wave][c1+k]=pa[k]; r8[wave][c2+k]=pa[4+k]; }
    __syncthreads();
    int c = tid;
    float pltot = 0.f;
    #pragma unroll
    for (int w=0;w<8;w++) pltot += r8[w][c];
    __syncthreads();
    #pragma unroll
    for (int k=0;k<4;k++){ r8[wave][c1+k]=sa[k]; r8[wave][c2+k]=sa[4+k]; }
    __syncthreads();
    float stot = 0.f;
    #pragma unroll
    for (int w=0;w<8;w++) stot += r8[w][c];
    __syncthreads();
    #pragma unroll
    for (int k=0;k<4;k++){ r8[wave][c1+k]=ma[k]; r8[wave][c2+k]=ma[4+k]; }
    __syncthreads();
    float mtot = -1e30f;
    #pragma unroll
    for (int w=0;w<8;w++) mtot = fmaxf(mtot, r8[w][c]);
    pooled[(size_t)b*C_+c] = pltot;
    float w40=vecs[VW4+0], w41=vecs[VW4+1];
    mm[(size_t)b*C_+c] = stot*(1.f/HW_)*w40 + mtot*w41;
}

// ---------- proj: v-proj -> c-proj -> xq -> yq (all coalesced) ----------
__global__ void __launch_bounds__(512) proj_kernel(const float* __restrict__ pooled,
        const float* __restrict__ mm, const float* __restrict__ vwt,
        const float* __restrict__ cwt, const void* __restrict__ dcw2,
        const float* __restrict__ vecs, float* __restrict__ xq,
        float* __restrict__ yq, const int* __restrict__ flag){
    bool f32 = flag[0]!=0;
    int b = blockIdx.x, c = threadIdx.x;       // 512 threads
    __shared__ float p_s[C_];
    __shared__ float pre_s[C_];
    __shared__ float xq_s[C_];
    p_s[c] = pooled[(size_t)b*C_ + c];
    __syncthreads();
    float pre = vecs[VVB+c];
    for (int i=0;i<C_;i++) pre += p_s[i]*vwt[(size_t)i*C_+c];
    pre_s[c] = pre;
    __syncthreads();
    float att = vecs[VCB+c];
    for (int i=0;i<C_;i++) att += pre_s[i]*cwt[(size_t)i*C_+c];
    float xqv = mm[(size_t)b*C_+c] + vecs[VW4+2]*att;
    xq[(size_t)b*C_+c] = xqv;
    xq_s[c] = xqv;
    __syncthreads();
    float yqv = 0.f;
    for (int i=0;i<C_;i++) yqv += xq_s[i]*ldd(dcw2, (size_t)i*C_+c, f32);
    yq[(size_t)b*C_+c] = yqv;
}

// ---------- corr2gz: fused gates + z-partials + x_down, frame-quarter blocks ----------
// grid (192 frames, 4 quarters) x 512 thr. Frame-quarter staged to LDS ONCE (rows
// padded to XR=516 shorts => 1032 B: 8B-aligned b64 reads, ~3-4-way max bank alias).
// Phase A: gates for the 6 target b's (wave-per-row). Phase B: z-partials
// (thread-per-e). Phase C (new, replaces xdown_kernel): x_down = W @ x from the
// SAME resident xs — wave handles 4 consecutive r (wave-uniform weight rows ->
// same-address float4 loads), lane = l.
#define QROWS 49
#define XR    516
#define B6C   (B_*6*C_)   // 589824
__global__ void __launch_bounds__(512) corr2gz_kernel(const bf16* __restrict__ xt,
        const float* __restrict__ yq, const float* __restrict__ vecs,
        const float* __restrict__ dwt, float* __restrict__ zpart,
        bf16* __restrict__ xd){
    const int offs[6] = {-3,-2,-1,1,2,3};
    int frame = blockIdx.x;            // n*T_ + t'
    int qq = blockIdx.y;               // row quarter
    int n = frame / T_, tp = frame % T_;
    int l0 = qq*QROWS;
    __shared__ bf16 xs[QROWS*XR];      // 50568 B
    __shared__ float a_s[6][QROWS];
    int tid = threadIdx.x, lane = tid&63, wave = tid>>6;
    // stage 49 rows, coalesced ushort4 (padded rows)
    const ushort4v* src = (const ushort4v*)(xt + ((size_t)frame*HW_ + l0)*C_);
    for (int i=tid; i<QROWS*128; i+=512){
        int row = i>>7, g4 = (i&127)*4;
        *(ushort4v*)(xs + row*XR + g4) = src[i];
    }
    // target validity + yq registers + weights
    bool val[6]; float w2r[6]; float yqr[6][8];
    #pragma unroll
    for (int jj=0;jj<6;jj++){
        int tt = tp - offs[jj];
        val[jj] = (tt>=0 && tt<T_);
        w2r[jj] = vecs[VW2+jj];
        if (val[jj]){
            const float* yb = yq + (size_t)(n*T_+tt)*C_;
            #pragma unroll
            for (int k=0;k<4;k++){ yqr[jj][k]=yb[lane*4+k]; yqr[jj][4+k]=yb[256+lane*4+k]; }
        } else {
            #pragma unroll
            for (int k=0;k<8;k++) yqr[jj][k]=0.f;
        }
    }
    __syncthreads();
    // ---- Phase A: gates, wave-per-row, 6 targets at once ----
    for (int li=wave; li<QROWS; li+=8){
        ushort4v u1 = *(const ushort4v*)(xs + li*XR + lane*4);
        ushort4v u2 = *(const ushort4v*)(xs + li*XR + 256 + lane*4);
        float xf[8];
        #pragma unroll
        for (int k=0;k<4;k++){ xf[k]=u2f(u1[k]); xf[4+k]=u2f(u2[k]); }
        float a[6];
        #pragma unroll
        for (int jj=0;jj<6;jj++){
            float s=0.f;
            #pragma unroll
            for (int k=0;k<8;k++) s += yqr[jj][k]*xf[k];
            a[jj]=s;
        }
        #pragma unroll
        for (int off=32; off>0; off>>=1){
            #pragma unroll
            for (int jj=0;jj<6;jj++) a[jj] += __shfl_down(a[jj], off);
        }
        if (lane==0){
            #pragma unroll
            for (int jj=0;jj<6;jj++)
                a_s[jj][li] = val[jj] ? w2r[jj]*(sigm(w2r[jj]*a[jj])-0.5f) : 0.f;
        }
    }
    __syncthreads();
    // ---- Phase B: z-partials, thread-per-e over the 49 staged rows ----
    {
        int e = tid;
        float acc[6] = {0.f,0.f,0.f,0.f,0.f,0.f};
        for (int li=0; li<QROWS; ++li){
            float xv = b2f(xs[li*XR + e]);
            #pragma unroll
            for (int jj=0;jj<6;jj++) acc[jj] += a_s[jj][li]*xv;
        }
        #pragma unroll
        for (int jj=0;jj<6;jj++){
            if (val[jj]){
                int b = n*T_ + (tp - offs[jj]);
                zpart[(size_t)qq*B6C + ((size_t)b*6+jj)*C_ + e] = acc[jj];
            }
        }
    }
    // ---- Phase C: x_down from resident xs (no barrier needed: xs read-only) ----
    {
        int r0 = __builtin_amdgcn_readfirstlane(wave)*4;   // wave-uniform
        if (lane < QROWS){
            const bf16* xr = xs + lane*XR;
            const float* w0 = dwt + (size_t)(r0+0)*C_;
            const float* w1 = dwt + (size_t)(r0+1)*C_;
            const float* w2p= dwt + (size_t)(r0+2)*C_;
            const float* w3 = dwt + (size_t)(r0+3)*C_;
            float a0=0.f, a1=0.f, a2=0.f, a3=0.f;
            for (int c4=0; c4<C_; c4+=4){
                ushort4v u = *(const ushort4v*)(xr + c4);
                float x0=u2f(u[0]), x1=u2f(u[1]), x2=u2f(u[2]), x3=u2f(u[3]);
                float4 wa = *(const float4*)(w0 + c4);
                float4 wb = *(const float4*)(w1 + c4);
                float4 wc = *(const float4*)(w2p+ c4);
                float4 wd = *(const float4*)(w3 + c4);
                a0 += wa.x*x0 + wa.y*x1 + wa.z*x2 + wa.w*x3;
                a1 += wb.x*x0 + wb.y*x1 + wb.z*x2 + wb.w*x3;
                a2 += wc.x*x0 + wc.y*x1 + wc.z*x2 + wc.w*x3;
                a3 += wd.x*x0 + wd.y*x1 + wd.z*x2 + wd.w*x3;
            }
            int gl = l0 + lane;
            size_t base = (((size_t)n*RC_ + r0)*T_ + tp)*HW_ + gl;
            size_t step = (size_t)T_*HW_;
            xd[base       ] = __float2bfloat16(a0);
            xd[base+  step] = __float2bfloat16(a1);
            xd[base+2*step] = __float2bfloat16(a2);
            xd[base+3*step] = __float2bfloat16(a3);
        }
    }
}

// ---------- corr2f: z = sum(valid zparts); feat[b][c] = sum_e w2t[e][c]*z[e] ----------
__global__ void __launch_bounds__(128) corr2f_kernel(const float* __restrict__ zpart,
        const float* __restrict__ w2t, float* __restrict__ feat){
    const int offs[6] = {-3,-2,-1,1,2,3};
    int b = blockIdx.x, c0 = blockIdx.y*128;
    int t = b % T_;
    int tid = threadIdx.x;
    __shared__ float z_s[C_];
    for (int e=tid; e<C_; e+=128){
        float s = 0.f;
        #pragma unroll
        for (int jj=0;jj<6;jj++){
            int tj = t + offs[jj];
            if (tj<0 || tj>=T_) continue;
            const float* zp = zpart + ((size_t)b*6+jj)*C_ + e;
            s += zp[0] + zp[B6C] + zp[2*B6C] + zp[3*(size_t)B6C];
        }
        z_s[e] = s;
    }
    __syncthreads();
    int c = c0 + tid;
    float acc = 0.f;
    for (int e=0;e<C_;e++) acc += w2t[(size_t)e*C_+c]*z_s[e];
    feat[(size_t)b*C_+c] = acc;
}

// ---------- dwconv: padded-tile version, one (n,r,t) per block ----------
#define TPAD 21
#define TROW 20
#define TFRM (TROW*TPAD)   // 420
__global__ void __launch_bounds__(256) dwconv_kernel(const bf16* __restrict__ xd,
        const float* __restrict__ saw, const float* __restrict__ vecs,
        float* __restrict__ aggs){
    int nr = blockIdx.x;            // n*RC_+r
    int t  = blockIdx.y;
    int r  = nr % RC_;
    __shared__ float tile[9*TFRM];
    __shared__ float wsm[3][81];
    int tid = threadIdx.x;          // 256
    for (int i=tid;i<9*TFRM;i+=256) tile[i] = 0.f;
    if (tid < 81){
        wsm[0][tid]=saw[       r*81+tid];
        wsm[1][tid]=saw[2592 + r*81+tid];
        wsm[2][tid]=saw[5184 + r*81+tid];
    }
    __syncthreads();
    const bf16* base = xd + (size_t)nr*T_*HW_;
    for (int i=tid;i<9*HW_;i+=256){
        int kt = i/HW_, hw = i - kt*HW_;
        int tg = t - 4 + kt;
        if (tg>=0 && tg<T_){
            int h = hw/W_, w = hw - h*W_;
            tile[kt*TFRM + (h+3)*TPAD + (w+3)] = b2f(base[(size_t)tg*HW_ + hw]);
        }
    }
    __syncthreads();
    if (tid < HW_){
        int h = tid/W_, w = tid - h*W_;
        float w0=vecs[VWTS+0], w1=vecs[VWTS+1], w2v=vecs[VWTS+2];
        float cbias = w0*vecs[VSAB+r] + w1*vecs[VSAB+32+r] + w2v*vecs[VSAB+64+r];
        float bacc[3];
        #pragma unroll
        for (int br=0;br<3;br++){
            int d = br+1;
            float s = 0.f;
            #pragma unroll
            for (int kt=0;kt<9;kt++){
                const float* tb = &tile[kt*TFRM + (h+3-d)*TPAD + (w+3-d)];
                const float* wp = &wsm[br][kt*9];
                s += wp[0]*tb[0]          + wp[1]*tb[d]          + wp[2]*tb[2*d]
                   + wp[3]*tb[d*TPAD]     + wp[4]*tb[d*TPAD+d]   + wp[5]*tb[d*TPAD+2*d]
                   + wp[6]*tb[2*d*TPAD]   + wp[7]*tb[2*d*TPAD+d] + wp[8]*tb[2*d*TPAD+2*d];
            }
            bacc[br] = s;
        }
        float acc = cbias + w0*bacc[0] + w1*bacc[1] + w2v*bacc[2];
        aggs[(size_t)nr*T_*HW_ + (size_t)t*HW_ + tid] = acc;
    }
}

// ---------- final: conv_back (reg-resident agg) + gate * feat -> fp32 out ----------
__global__ void __launch_bounds__(256) final_kernel(const float* __restrict__ aggs,
                                                    const float* __restrict__ cbwf,
                                                    const float* __restrict__ feat,
                                                    float* __restrict__ out){
    int b = blockIdx.x, n = b/T_, t = b%T_;
    int c0 = blockIdx.y*128;
    int hw = threadIdx.x;
    if (hw >= HW_) return;
    float ra[RC_];
    #pragma unroll
    for (int r=0;r<RC_;r++)
        ra[r] = aggs[(((size_t)n*RC_+r)*T_ + t)*HW_ + hw];
    const float* fb = feat + (size_t)b*C_;
    for (int ci=0;ci<128;ci++){
        int c = c0+ci;
        const float* wr = cbwf + c*RC_;    // wave-uniform
        float a = 0.f;
        #pragma unroll
        for (int r=0;r<RC_;r++) a += wr[r]*ra[r];
        out[(((size_t)n*C_+c)*T_ + t)*HW_ + hw] = fb[c]*(sigm(a)-0.5f);
    }
}

extern "C" void kernel_launch(void* const* d_in, const int* in_sizes, int n_in,
                              void* d_out, int out_size, void* d_ws, size_t ws_size,
                              hipStream_t stream){
    const void* x      = d_in[0];
    const void* dcw2   = d_in[1];
    const void* dcw    = d_in[2];
    const void* cbw    = d_in[3];
    const void* w2     = d_in[4];
    const void* w4     = d_in[5];
    const void* wts    = d_in[6];
    const void* query  = d_in[7];
    const void* q_w    = d_in[8];
    const void* q_b    = d_in[9];
    const void* k_w    = d_in[10];
    const void* k_b    = d_in[11];
    const void* v_w    = d_in[12];
    const void* v_b    = d_in[13];
    const void* c_w    = d_in[14];
    const void* c_b    = d_in[15];
    const void* sa1w   = d_in[16];
    const void* sa1b   = d_in[17];
    const void* sa2w   = d_in[18];
    const void* sa2b   = d_in[19];
    const void* sa3w   = d_in[20];
    const void* sa3b   = d_in[21];
    float* out = (float*)d_out;

    // workspace layout — ~12.5 MB
    float* ws    = (float*)d_ws;
    int*   flag  = (int*)ws;               // 16
    float* qk    = ws + 16;                // 1024
    float* qp    = qk + 1024;              // 1024 (uses 512)
    float* pooled= qp + 1024;              // 98304
    float* mm    = pooled + 98304;         // 98304
    float* xq    = mm + 98304;             // 98304
    float* yq    = xq + 98304;             // 98304
    float* feat  = yq + 98304;             // 98304
    float* w2t   = feat + 98304;           // 262144
    float* vwt   = w2t + 262144;           // 262144
    float* cwt   = vwt + 262144;           // 262144
    float* dwt   = cwt + 262144;           // 16384
    float* cbwf  = dwt + 16384;            // 16384
    float* saw   = cbwf + 16384;           // 7936 (uses 7776)
    float* vecs  = saw + 7936;             // 2720
    float* aggs  = vecs + VECS_TOTAL;      // 1204224 fp32
    bf16*  xd    = (bf16*)(aggs + 1204224);// 1204224 bf16
    // xt (channel-last bf16 x) in first 38.5 MB of d_out; zpart (4x2.36 MB)
    // in the next 9.4 MB. Both fully consumed before final_kernel writes d_out.
    bf16*  xt    = (bf16*)d_out;
    float* zpart = (float*)(xt + (size_t)XTOT);

    probe_kernel<<<1, 64, 0, stream>>>(x, flag);
    prep_w2t_kernel<<<(C_*C_+255)/256, 256, 0, stream>>>(dcw2, w2t, flag);
    prep_misc_kernel<<<(PM_TOTAL+255)/256, 256, 0, stream>>>(
        dcw, cbw, sa1w, sa2w, sa3w, q_b, k_b, v_b, c_b, query,
        sa1b, sa2b, sa3b, w2, w4, wts, v_w, c_w,
        dwt, cbwf, saw, vecs, vwt, cwt, flag);
    cvt_tr_kernel<<<dim3(B_, C_/TCH), 256, 0, stream>>>(x, xt, flag);

    qproj1_kernel<<<C_, 64, 0, stream>>>(q_w, vecs, qp, flag);
    qproj2_kernel<<<9, 256, 0, stream>>>(k_w, vecs, qp, qk, flag);
    f1_kernel<<<B_, 512, 0, stream>>>(xt, qk, vecs, pooled, mm);
    proj_kernel<<<B_, C_, 0, stream>>>(pooled, mm, vwt, cwt, dcw2, vecs, xq, yq, flag);

    corr2gz_kernel<<<dim3(B_, 4), 512, 0, stream>>>(xt, yq, vecs, dwt, zpart, xd);
    corr2f_kernel<<<dim3(B_, 4), 128, 0, stream>>>(zpart, w2t, feat);

    dwconv_kernel<<<dim3(N_*RC_, T_), 256, 0, stream>>>(xd, saw, vecs, aggs);
    final_kernel<<<dim3(B_, 4), 256, 0, stream>>>(aggs, cbwf, feat, out);
}